// Round 3
// baseline (602.168 us; speedup 1.0000x reference)
//
#include <hip/hip_runtime.h>
#include <math.h>

// Problem constants
#define NT   8192          // N*T rows
#define UV   4096          // U*B cells
#define SDIM 128
#define LOG1EM6 -13.815510557964274f

// d_out layout (float offsets): delta[8192][256], sig[8192][128], conf[8192],
// weights[8192][4096], topw[8192]
#define O_DELTA 0
#define O_SIG   2097152
#define O_CONF  3145728
#define O_W     3153920
#define O_TOPW  36708352

// d_ws layout (float offsets)
#define W_K4P   0              // k4 split-1 partial [8192][384] (reuses dead regions below)
#define W_QSHI  0              // qs normalized, bf16 hi [8192][128] ushort (dead after k3)
#define W_QSLO  524288
#define W_SPHI  1048576        // spn normalized, bf16 hi [4096][128] ushort (dead after k3)
#define W_SPLO  1310720
#define W_LQU   1572864        // log(q_u) [8192][64] (dead after k3)
#define W_LQB   2097152        // log(q_b) [8192][64] (dead after k3)
#define W_BIAS  2621440        // 0.5*usage_n + 0.5*conf_n [4096] (dead after k3)
#define W_CONFN 2625536        // conf_n [4096] (dead after k3b)
#define W_VALID 2629632        // validity [4096] (dead after k3)
#define W_PSUM  2633728        // per-colblock row partials [32][8192] (dead after k3b)
#define W_PMAX  2895872
#define W_PSIG  3158016
#define W_PUV   3420160
#define W_RINV  3682304        // 1/rowsum [8192] (dead after k3c)
#define W_PTHI  3690496        // proto split bf16 hi, [384 n][4096 k] ushort (live through k4)
#define W_PTLO  4476928
// total ws usage: 5263360 floats = 21.1 MB
// k4 partial = 3145728 floats at [0, 3145728) -- fits entirely in the
// QSHI..PUV region (all dead once k3b/k3c complete), ends before W_RINV.

typedef __attribute__((ext_vector_type(8))) short short8;
typedef __attribute__((ext_vector_type(4))) float floatx4;

__device__ __forceinline__ unsigned short f2bf(float x) {
    unsigned u = __builtin_bit_cast(unsigned, x);
    u = u + 0x7fffu + ((u >> 16) & 1u);          // round-to-nearest-even
    return (unsigned short)(u >> 16);
}
__device__ __forceinline__ float bf2f(unsigned short h) {
    unsigned u = ((unsigned)h) << 16;
    return __builtin_bit_cast(float, u);
}

// ---------------------------------------------------------------------------
// K1: global maxes over write_mass/ema_conf -> bias/conf/valid tables.
// ---------------------------------------------------------------------------
__global__ void k1_tables(const float* __restrict__ wm,
                          const float* __restrict__ ec,
                          float* __restrict__ ws)
{
    __shared__ float red1[256];
    __shared__ float red2[256];
    const int tid = threadIdx.x;
    float m1 = 0.0f, m2 = 0.0f;
    for (int i = tid; i < UV; i += 256) {
        m1 = fmaxf(m1, log1pf(wm[i]));
        m2 = fmaxf(m2, ec[i]);
    }
    red1[tid] = m1; red2[tid] = m2;
    __syncthreads();
    for (int s = 128; s > 0; s >>= 1) {
        if (tid < s) {
            red1[tid] = fmaxf(red1[tid], red1[tid + s]);
            red2[tid] = fmaxf(red2[tid], red2[tid + s]);
        }
        __syncthreads();
    }
    const float inv1 = 1.0f / fmaxf(red1[0], 1.0f);
    const float inv2 = 1.0f / fmaxf(red2[0], 1e-6f);
    for (int i = tid; i < UV; i += 256) {
        float w  = wm[i];
        float un = log1pf(w) * inv1;
        float cn = ec[i] * inv2;
        ws[W_BIAS  + i] = 0.5f * un + 0.5f * cn;
        ws[W_CONFN + i] = cn;
        ws[W_VALID + i] = (w > 0.0f) ? 1.0f : 0.0f;
    }
}

// ---------------------------------------------------------------------------
// K2: l2-normalize signature_proto(+1e-6) and q_sigma rows; emit bf16 hi/lo.
// ---------------------------------------------------------------------------
__global__ void k2_norm(const float* __restrict__ spr,
                        const float* __restrict__ qsig,
                        float* __restrict__ ws)
{
    const int wid  = blockIdx.x * 4 + (threadIdx.x >> 6);   // 0..12287
    const int lane = threadIdx.x & 63;
    if (wid < UV) {
        const float* src = spr + (size_t)wid * SDIM;
        float a = src[lane] + 1e-6f;
        float b = src[lane + 64] + 1e-6f;
        float ss = a * a + b * b;
        for (int m = 32; m > 0; m >>= 1) ss += __shfl_xor(ss, m);
        float inv = 1.0f / fmaxf(sqrtf(ss), 1e-12f);
        a *= inv; b *= inv;
        unsigned short* hi = (unsigned short*)(ws + W_SPHI);
        unsigned short* lo = (unsigned short*)(ws + W_SPLO);
        unsigned short ha = f2bf(a), hb = f2bf(b);
        hi[wid * 128 + lane]      = ha;
        hi[wid * 128 + lane + 64] = hb;
        lo[wid * 128 + lane]      = f2bf(a - bf2f(ha));
        lo[wid * 128 + lane + 64] = f2bf(b - bf2f(hb));
    } else {
        const int row = wid - UV;
        const float* src = qsig + (size_t)row * SDIM;
        float a = src[lane];
        float b = src[lane + 64];
        float ss = a * a + b * b;
        for (int m = 32; m > 0; m >>= 1) ss += __shfl_xor(ss, m);
        float inv = 1.0f / fmaxf(sqrtf(ss), 1e-12f);
        a *= inv; b *= inv;
        unsigned short* hi = (unsigned short*)(ws + W_QSHI);
        unsigned short* lo = (unsigned short*)(ws + W_QSLO);
        unsigned short ha = f2bf(a), hb = f2bf(b);
        hi[row * 128 + lane]      = ha;
        hi[row * 128 + lane + 64] = hb;
        lo[row * 128 + lane]      = f2bf(a - bf2f(ha));
        lo[row * 128 + lane + 64] = f2bf(b - bf2f(hb));
    }
}

// ---------------------------------------------------------------------------
// K2b: transpose protos into [n][k] layout and split into bf16 hi/lo pairs.
// ---------------------------------------------------------------------------
__global__ __launch_bounds__(256)
void k2b_protoT(const float* __restrict__ drp, const float* __restrict__ spr,
                float* __restrict__ ws)
{
    __shared__ float tile[32][33];
    const int tid = threadIdx.x;
    const int k0 = blockIdx.x * 32;
    const int n0 = blockIdx.y * 32;
    {
        const int kr = tid >> 3, nc = (tid & 7) * 4;
        const int n = n0 + nc;
        float4 v;
        if (n < 256) v = *(const float4*)&drp[(size_t)(k0 + kr) * 256 + n];
        else         v = *(const float4*)&spr[(size_t)(k0 + kr) * 128 + (n - 256)];
        tile[kr][nc] = v.x; tile[kr][nc + 1] = v.y;
        tile[kr][nc + 2] = v.z; tile[kr][nc + 3] = v.w;
    }
    __syncthreads();
    {
        const int nr = tid >> 3, kc = (tid & 7) * 4;
        unsigned short* pth = (unsigned short*)(ws + W_PTHI);
        unsigned short* ptl = (unsigned short*)(ws + W_PTLO);
        ushort4 h, l;
        float x;
        x = tile[kc + 0][nr]; h.x = f2bf(x); l.x = f2bf(x - bf2f(h.x));
        x = tile[kc + 1][nr]; h.y = f2bf(x); l.y = f2bf(x - bf2f(h.y));
        x = tile[kc + 2][nr]; h.z = f2bf(x); l.z = f2bf(x - bf2f(h.z));
        x = tile[kc + 3][nr]; h.w = f2bf(x); l.w = f2bf(x - bf2f(h.w));
        *(ushort4*)&pth[(size_t)(n0 + nr) * 4096 + k0 + kc] = h;
        *(ushort4*)&ptl[(size_t)(n0 + nr) * 4096 + k0 + kc] = l;
    }
}

// ---------------------------------------------------------------------------
// K2c: log tables for q_u / q_b: lqu[row][64], lqb[row][64].
// ---------------------------------------------------------------------------
__global__ __launch_bounds__(256)
void k2c_logs(const float* __restrict__ qu, const float* __restrict__ qb,
              float* __restrict__ ws)
{
    const int t = blockIdx.x * 256 + threadIdx.x;           // 512 blocks
    const float* src = blockIdx.y ? qb : qu;
    float* dst = ws + (blockIdx.y ? W_LQB : W_LQU);
    float4 v = *(const float4*)&src[t * 4];
    v.x = __logf(v.x); v.y = __logf(v.y);
    v.z = __logf(v.z); v.w = __logf(v.w);
    *(float4*)&dst[t * 4] = v;
}

// ---------------------------------------------------------------------------
// K3: MFMA GEMM1 (qs . spn^T, 3-term bf16 split) fused with logits + exp +
// per-row partial stats. BM=64 BN=128 BK=32 (K=128, 4 chunks), 256 threads
// (2x2 waves), grid (128 row-tiles, 32 col-blocks). Term-major MFMA order.
// ---------------------------------------------------------------------------
#define SA3 40

__global__ __launch_bounds__(256, 4)
void k3_mfma(float* __restrict__ ws, float* __restrict__ dout)
{
    __shared__ unsigned short sAh[64 * SA3];
    __shared__ unsigned short sAl[64 * SA3];
    __shared__ unsigned short sBh[128 * SA3];
    __shared__ unsigned short sBl[128 * SA3];
    __shared__ float sS[2][64], sM[2][64], sG[2][64], sU[2][64];

    const int tid  = threadIdx.x;
    const int row0 = blockIdx.x * 64;
    const int cb   = blockIdx.y;
    const int n0   = cb * 128;

    const unsigned short* qsh = (const unsigned short*)(ws + W_QSHI);
    const unsigned short* qsl = (const unsigned short*)(ws + W_QSLO);
    const unsigned short* sph = (const unsigned short*)(ws + W_SPHI);
    const unsigned short* spl = (const unsigned short*)(ws + W_SPLO);

    const int tAr = tid >> 2;
    const int tAk = (tid & 3) * 8;
    const int tBn = tid >> 2;
    const int tBk = (tid & 3) * 8;

    uint4 pah, pal, pbh[2], pbl[2];
    {
        pah = *(const uint4*)&qsh[(size_t)(row0 + tAr) * 128 + tAk];
        pal = *(const uint4*)&qsl[(size_t)(row0 + tAr) * 128 + tAk];
        #pragma unroll
        for (int p = 0; p < 2; ++p) {
            pbh[p] = *(const uint4*)&sph[(size_t)(n0 + tBn + p * 64) * 128 + tBk];
            pbl[p] = *(const uint4*)&spl[(size_t)(n0 + tBn + p * 64) * 128 + tBk];
        }
    }

    const int lane = tid & 63;
    const int wid  = tid >> 6;
    const int wm   = wid & 1;
    const int wn   = wid >> 1;
    const int fr   = lane & 15;
    const int fq   = lane >> 4;
    const int ako  = fq * 8;

    floatx4 acc[2][4];
    #pragma unroll
    for (int mt = 0; mt < 2; ++mt)
        #pragma unroll
        for (int nt = 0; nt < 4; ++nt)
            acc[mt][nt] = (floatx4){0.f, 0.f, 0.f, 0.f};

    for (int kc = 0; kc < 4; ++kc) {
        __syncthreads();
        *(uint4*)&sAh[tAr * SA3 + tAk] = pah;
        *(uint4*)&sAl[tAr * SA3 + tAk] = pal;
        #pragma unroll
        for (int p = 0; p < 2; ++p) {
            *(uint4*)&sBh[(tBn + p * 64) * SA3 + tBk] = pbh[p];
            *(uint4*)&sBl[(tBn + p * 64) * SA3 + tBk] = pbl[p];
        }
        __syncthreads();

        if (kc < 3) {
            const int kn = (kc + 1) * 32;
            pah = *(const uint4*)&qsh[(size_t)(row0 + tAr) * 128 + kn + tAk];
            pal = *(const uint4*)&qsl[(size_t)(row0 + tAr) * 128 + kn + tAk];
            #pragma unroll
            for (int p = 0; p < 2; ++p) {
                pbh[p] = *(const uint4*)&sph[(size_t)(n0 + tBn + p * 64) * 128 + kn + tBk];
                pbl[p] = *(const uint4*)&spl[(size_t)(n0 + tBn + p * 64) * 128 + kn + tBk];
            }
        }

        short8 afh[2], afl[2], bfh[4], bfl[4];
        #pragma unroll
        for (int mt = 0; mt < 2; ++mt) {
            const int m = wm * 32 + mt * 16 + fr;
            afh[mt] = *(const short8*)&sAh[m * SA3 + ako];
            afl[mt] = *(const short8*)&sAl[m * SA3 + ako];
        }
        #pragma unroll
        for (int nt = 0; nt < 4; ++nt) {
            const int n = wn * 64 + nt * 16 + fr;
            bfh[nt] = *(const short8*)&sBh[n * SA3 + ako];
            bfl[nt] = *(const short8*)&sBl[n * SA3 + ako];
        }
        // term-major: 8 independent MFMAs back-to-back per term
        #pragma unroll
        for (int mt = 0; mt < 2; ++mt)
            #pragma unroll
            for (int nt = 0; nt < 4; ++nt)
                acc[mt][nt] = __builtin_amdgcn_mfma_f32_16x16x32_bf16(
                    afh[mt], bfh[nt], acc[mt][nt], 0, 0, 0);
        #pragma unroll
        for (int mt = 0; mt < 2; ++mt)
            #pragma unroll
            for (int nt = 0; nt < 4; ++nt)
                acc[mt][nt] = __builtin_amdgcn_mfma_f32_16x16x32_bf16(
                    afh[mt], bfl[nt], acc[mt][nt], 0, 0, 0);
        #pragma unroll
        for (int mt = 0; mt < 2; ++mt)
            #pragma unroll
            for (int nt = 0; nt < 4; ++nt)
                acc[mt][nt] = __builtin_amdgcn_mfma_f32_16x16x32_bf16(
                    afl[mt], bfh[nt], acc[mt][nt], 0, 0, 0);
    }

    // --- epilogue: logits -> e (unnormalized), partial row stats -----------
    const float* lqu    = ws + W_LQU;
    const float* lqb    = ws + W_LQB;
    const float* bias   = ws + W_BIAS;
    const float* validf = ws + W_VALID;
    float* wout = dout + O_W;

    float ps[2][4], pm[2][4], pg[2][4], pu[2][4];
    #pragma unroll
    for (int mt = 0; mt < 2; ++mt)
        #pragma unroll
        for (int r = 0; r < 4; ++r) {
            ps[mt][r] = 0.f; pm[mt][r] = -1e30f; pg[mt][r] = 0.f; pu[mt][r] = 0.f;
        }

    #pragma unroll
    for (int mt = 0; mt < 2; ++mt) {
        const int rbase = row0 + wm * 32 + mt * 16 + fq * 4;
        #pragma unroll
        for (int nt = 0; nt < 4; ++nt) {
            const int uvb = n0 + wn * 64 + nt * 16;
            const int u   = uvb >> 6;
            const int uv  = uvb + fr;
            const int v   = uv & 63;
            const float bv = bias[uv];
            const float vd = validf[uv];
            const floatx4 a = acc[mt][nt];
            #pragma unroll
            for (int reg = 0; reg < 4; ++reg) {
                const int row = rbase + reg;
                const float jl  = fmaxf(lqu[(row << 6) + u] + lqb[(row << 6) + v], LOG1EM6);
                const float sig = fmaf(0.5f, a[reg], 0.5f);
                const float lg  = jl + bv + sig;
                const float e   = (vd > 0.f) ? __expf(lg - 2.f) : 0.f;
                wout[((size_t)row << 12) + uv] = e;
                ps[mt][reg] += e;
                if (vd > 0.f && lg > pm[mt][reg]) {
                    pm[mt][reg] = lg; pu[mt][reg] = (float)uv; pg[mt][reg] = sig;
                }
            }
        }
    }

    #pragma unroll
    for (int off = 1; off < 16; off <<= 1) {
        #pragma unroll
        for (int mt = 0; mt < 2; ++mt)
            #pragma unroll
            for (int r = 0; r < 4; ++r) {
                ps[mt][r] += __shfl_xor(ps[mt][r], off);
                float om = __shfl_xor(pm[mt][r], off);
                float ou = __shfl_xor(pu[mt][r], off);
                float og = __shfl_xor(pg[mt][r], off);
                if (om > pm[mt][r] || (om == pm[mt][r] && ou < pu[mt][r])) {
                    pm[mt][r] = om; pu[mt][r] = ou; pg[mt][r] = og;
                }
            }
    }
    if (fr == 0) {
        #pragma unroll
        for (int mt = 0; mt < 2; ++mt)
            #pragma unroll
            for (int r = 0; r < 4; ++r) {
                const int rl = wm * 32 + mt * 16 + fq * 4 + r;
                sS[wn][rl] = ps[mt][r]; sM[wn][rl] = pm[mt][r];
                sG[wn][rl] = pg[mt][r]; sU[wn][rl] = pu[mt][r];
            }
    }
    __syncthreads();
    if (tid < 64) {
        const float s  = sS[0][tid] + sS[1][tid];
        const float m0 = sM[0][tid], m1 = sM[1][tid];
        float m, uvf, g;
        if (m0 > m1 || (m0 == m1 && sU[0][tid] <= sU[1][tid])) {
            m = m0; uvf = sU[0][tid]; g = sG[0][tid];
        } else {
            m = m1; uvf = sU[1][tid]; g = sG[1][tid];
        }
        const int row = row0 + tid;
        ws[W_PSUM + cb * NT + row] = s;
        ws[W_PMAX + cb * NT + row] = m;
        ws[W_PSIG + cb * NT + row] = g;
        ws[W_PUV  + cb * NT + row] = uvf;
    }
}

// ---------------------------------------------------------------------------
// K3b: combine 32 col-block partials per row -> rinv, top_weight, conf.
// ---------------------------------------------------------------------------
__global__ __launch_bounds__(256)
void k3b_stats(float* __restrict__ ws, float* __restrict__ dout)
{
    const int row = blockIdx.x * 256 + threadIdx.x;         // 32 blocks
    float s = 0.f, m = -1e30f, uvf = 0.f, g = 0.f;
    for (int cb = 0; cb < 32; ++cb) {
        s += ws[W_PSUM + cb * NT + row];
        const float om = ws[W_PMAX + cb * NT + row];
        const float ou = ws[W_PUV  + cb * NT + row];
        const float og = ws[W_PSIG + cb * NT + row];
        if (om > m || (om == m && ou < uvf)) { m = om; uvf = ou; g = og; }
    }
    const float inv = 1.0f / s;
    ws[W_RINV + row] = inv;
    const float topw = __expf(m - 2.f) * inv;
    dout[O_TOPW + row] = topw;
    const int uvi = (int)uvf;
    const float cf = topw * ws[W_CONFN + uvi] * g;
    dout[O_CONF + row] = fminf(fmaxf(cf, 0.f), 1.f);
}

// ---------------------------------------------------------------------------
// K3c: normalize weights in place (e -> w), wide grid-strided float4 sweep.
// ---------------------------------------------------------------------------
__global__ __launch_bounds__(256)
void k3c_scale(const float* __restrict__ ws, float* __restrict__ dout)
{
    float4* wb = (float4*)(dout + O_W);
    const float* rinv = ws + W_RINV;
    const int t = blockIdx.x * 256 + threadIdx.x;           // 2048 blocks
    #pragma unroll 4
    for (int i = 0; i < 16; ++i) {
        const int idx = t + i * 524288;
        const float r = rinv[idx >> 10];
        float4 v = wb[idx];
        v.x *= r; v.y *= r; v.z *= r; v.w *= r;
        wb[idx] = v;
    }
}

// ---------------------------------------------------------------------------
// K4: MFMA GEMM2/3, 3-term bf16 split, K-split 2, NO atomics. BM=64 BN=192,
// now 512 THREADS (8 waves, 2x4 wave grid; each wave owns 32x48 output).
// grid (128 rowtiles, 2 coltiles, 2 ksplits) = 512 blocks, 2 blocks/CU via
// 40KB LDS -> 16 waves/CU (was 8). Traffic identical to the 256-thread
// version; only latency-hiding capacity doubles (round-2 counters showed
// the latency/occupancy signature: Occ 20%, Mfma 12%, VALU 9%, HBM 20%).
// ksplit 0 plain-stores partial C into d_out; ksplit 1 into ws[W_K4P];
// k4b adds them. Term-major MFMA order: 6 independent MFMAs per term.
// ---------------------------------------------------------------------------
#define SA 40

__global__ __launch_bounds__(512, 4)
void k4_mfma(float* __restrict__ ws, float* __restrict__ dout)
{
    __shared__ unsigned short sAh[64 * SA];
    __shared__ unsigned short sAl[64 * SA];
    __shared__ unsigned short sBh[192 * SA];
    __shared__ unsigned short sBl[192 * SA];

    const int tid  = threadIdx.x;
    const int row0 = blockIdx.x * 64;
    const int n0g  = blockIdx.y * 192;
    const int kb   = blockIdx.z * 2048;      // K-split base

    const float* wsrc = dout + O_W;
    const unsigned short* pth = (const unsigned short*)(ws + W_PTHI);
    const unsigned short* ptl = (const unsigned short*)(ws + W_PTLO);

    // A staging: 64 rows x 32 k-ushorts; one float4 load per thread.
    const int ar  = tid >> 3;               // 0..63
    const int akg = tid & 7;                // 4-float chunk in k
    // B staging: flat 16B chunks. 192 rows x 4 chunks x 2 planes = 1536;
    // 512 threads x 3 chunks each.
    int b_row[3], b_kg[3], b_pl[3];
    #pragma unroll
    for (int p = 0; p < 3; ++p) {
        const int c  = tid + p * 512;       // 0..1535
        const int pl = (c >= 768) ? 1 : 0;
        const int cc = c - pl * 768;
        b_row[p] = cc >> 2;                 // 0..191
        b_kg[p]  = (cc & 3) * 8;            // ushort offset in k
        b_pl[p]  = pl;
    }

    float4 ap;
    uint4  bq[3];
    {
        ap = *(const float4*)&wsrc[(size_t)(row0 + ar) * UV + kb + akg * 4];
        #pragma unroll
        for (int p = 0; p < 3; ++p) {
            const unsigned short* bs = b_pl[p] ? ptl : pth;
            bq[p] = *(const uint4*)&bs[(size_t)(n0g + b_row[p]) * UV + kb + b_kg[p]];
        }
    }

    const int lane = tid & 63;
    const int wid  = tid >> 6;              // 0..7
    const int wm   = wid & 1;               // 2 row-waves (32 rows each)
    const int wn   = wid >> 1;              // 4 col-waves (48 cols each)
    const int fr   = lane & 15;
    const int fq   = lane >> 4;
    const int ako  = fq * 8;

    floatx4 acc[2][3];
    #pragma unroll
    for (int mt = 0; mt < 2; ++mt)
        #pragma unroll
        for (int nt = 0; nt < 3; ++nt)
            acc[mt][nt] = (floatx4){0.f, 0.f, 0.f, 0.f};

    for (int kc = 0; kc < 64; ++kc) {
        __syncthreads();
        {
            const float xs[4] = {ap.x, ap.y, ap.z, ap.w};
            ushort4 h, l;
            h.x = f2bf(xs[0]); l.x = f2bf(xs[0] - bf2f(h.x));
            h.y = f2bf(xs[1]); l.y = f2bf(xs[1] - bf2f(h.y));
            h.z = f2bf(xs[2]); l.z = f2bf(xs[2] - bf2f(h.z));
            h.w = f2bf(xs[3]); l.w = f2bf(xs[3] - bf2f(h.w));
            *(ushort4*)&sAh[ar * SA + akg * 4] = h;
            *(ushort4*)&sAl[ar * SA + akg * 4] = l;
        }
        #pragma unroll
        for (int p = 0; p < 3; ++p) {
            unsigned short* bd = b_pl[p] ? sBl : sBh;
            *(uint4*)&bd[b_row[p] * SA + b_kg[p]] = bq[p];
        }
        __syncthreads();

        if (kc + 1 < 64) {
            const int kn = kb + (kc + 1) * 32;
            ap = *(const float4*)&wsrc[(size_t)(row0 + ar) * UV + kn + akg * 4];
            #pragma unroll
            for (int p = 0; p < 3; ++p) {
                const unsigned short* bs = b_pl[p] ? ptl : pth;
                bq[p] = *(const uint4*)&bs[(size_t)(n0g + b_row[p]) * UV + kn + b_kg[p]];
            }
        }

        short8 afh[2], afl[2], bfh[3], bfl[3];
        #pragma unroll
        for (int mt = 0; mt < 2; ++mt) {
            const int m = wm * 32 + mt * 16 + fr;
            afh[mt] = *(const short8*)&sAh[m * SA + ako];
            afl[mt] = *(const short8*)&sAl[m * SA + ako];
        }
        #pragma unroll
        for (int nt = 0; nt < 3; ++nt) {
            const int n = wn * 48 + nt * 16 + fr;
            bfh[nt] = *(const short8*)&sBh[n * SA + ako];
            bfl[nt] = *(const short8*)&sBl[n * SA + ako];
        }
        // term-major: 6 independent MFMAs back-to-back per term
        #pragma unroll
        for (int mt = 0; mt < 2; ++mt)
            #pragma unroll
            for (int nt = 0; nt < 3; ++nt)
                acc[mt][nt] = __builtin_amdgcn_mfma_f32_16x16x32_bf16(
                    afh[mt], bfh[nt], acc[mt][nt], 0, 0, 0);
        #pragma unroll
        for (int mt = 0; mt < 2; ++mt)
            #pragma unroll
            for (int nt = 0; nt < 3; ++nt)
                acc[mt][nt] = __builtin_amdgcn_mfma_f32_16x16x32_bf16(
                    afh[mt], bfl[nt], acc[mt][nt], 0, 0, 0);
        #pragma unroll
        for (int mt = 0; mt < 2; ++mt)
            #pragma unroll
            for (int nt = 0; nt < 3; ++nt)
                acc[mt][nt] = __builtin_amdgcn_mfma_f32_16x16x32_bf16(
                    afl[mt], bfh[nt], acc[mt][nt], 0, 0, 0);
    }

    // epilogue: plain stores (split0 -> dout, split1 -> ws partial)
    #pragma unroll
    for (int mt = 0; mt < 2; ++mt) {
        #pragma unroll
        for (int nt = 0; nt < 3; ++nt) {
            const int gr0 = row0 + wm * 32 + mt * 16 + fq * 4;
            const int gc  = n0g + wn * 48 + nt * 16 + fr;
            const floatx4 a = acc[mt][nt];
            if (blockIdx.z == 0) {
                if (gc < 256) {
                    float* o = dout + O_DELTA;
                    o[(size_t)(gr0 + 0) * 256 + gc] = a[0];
                    o[(size_t)(gr0 + 1) * 256 + gc] = a[1];
                    o[(size_t)(gr0 + 2) * 256 + gc] = a[2];
                    o[(size_t)(gr0 + 3) * 256 + gc] = a[3];
                } else {
                    float* o = dout + O_SIG;
                    const int c = gc - 256;
                    o[(size_t)(gr0 + 0) * 128 + c] = a[0];
                    o[(size_t)(gr0 + 1) * 128 + c] = a[1];
                    o[(size_t)(gr0 + 2) * 128 + c] = a[2];
                    o[(size_t)(gr0 + 3) * 128 + c] = a[3];
                }
            } else {
                float* p = ws + W_K4P;
                p[(size_t)(gr0 + 0) * 384 + gc] = a[0];
                p[(size_t)(gr0 + 1) * 384 + gc] = a[1];
                p[(size_t)(gr0 + 2) * 384 + gc] = a[2];
                p[(size_t)(gr0 + 3) * 384 + gc] = a[3];
            }
        }
    }
}

// ---------------------------------------------------------------------------
// K4b: dout(delta|sig) += ws partial from ksplit 1. 786432 float4 elements.
// ---------------------------------------------------------------------------
__global__ __launch_bounds__(256)
void k4b_reduce(const float* __restrict__ ws, float* __restrict__ dout)
{
    const int idx = blockIdx.x * 256 + threadIdx.x;         // 3072 blocks
    const int row = idx / 96;                               // 96 float4-cols per row
    const int c   = (idx - row * 96) * 4;
    const float4 p = *(const float4*)&ws[W_K4P + (size_t)row * 384 + c];
    float* dst = (c < 256) ? (dout + O_DELTA + (size_t)row * 256 + c)
                           : (dout + O_SIG   + (size_t)row * 128 + (c - 256));
    float4 d = *(float4*)dst;
    d.x += p.x; d.y += p.y; d.z += p.z; d.w += p.w;
    *(float4*)dst = d;
}

// ---------------------------------------------------------------------------
extern "C" void kernel_launch(void* const* d_in, const int* in_sizes, int n_in,
                              void* d_out, int out_size, void* d_ws, size_t ws_size,
                              hipStream_t stream)
{
    const float* qu   = (const float*)d_in[0];
    const float* qb   = (const float*)d_in[1];
    const float* qsig = (const float*)d_in[2];
    const float* drp  = (const float*)d_in[3];
    const float* spr  = (const float*)d_in[4];
    const float* wm   = (const float*)d_in[5];
    const float* ec   = (const float*)d_in[6];
    float* out = (float*)d_out;
    float* ws  = (float*)d_ws;

    k1_tables<<<1, 256, 0, stream>>>(wm, ec, ws);
    k2_norm<<<3072, 256, 0, stream>>>(spr, qsig, ws);
    k2b_protoT<<<dim3(128, 12), 256, 0, stream>>>(drp, spr, ws);
    k2c_logs<<<dim3(512, 2), 256, 0, stream>>>(qu, qb, ws);
    k3_mfma<<<dim3(128, 32), 256, 0, stream>>>(ws, out);
    k3b_stats<<<32, 256, 0, stream>>>(ws, out);
    k3c_scale<<<2048, 256, 0, stream>>>(ws, out);
    k4_mfma<<<dim3(128, 2, 2), 512, 0, stream>>>(ws, out);
    k4b_reduce<<<3072, 256, 0, stream>>>(ws, out);
}

// Round 4
// 433.465 us; speedup vs baseline: 1.3892x; 1.3892x over previous
//
#include <hip/hip_runtime.h>
#include <math.h>

// Problem constants
#define NT   8192          // N*T rows
#define UV   4096          // U*B cells
#define SDIM 128
#define LOG1EM6 -13.815510557964274f

// d_out layout (float offsets): delta[8192][256], sig[8192][128], conf[8192],
// weights[8192][4096], topw[8192]
#define O_DELTA 0
#define O_SIG   2097152
#define O_CONF  3145728
#define O_W     3153920
#define O_TOPW  36708352

// d_ws layout (float offsets)
#define W_K4P   0              // k4 split-1 partial [8192][384] (reuses dead regions below)
#define W_QSHI  0              // qs normalized, bf16 hi [8192][128] ushort (dead after k3)
#define W_QSLO  524288
#define W_SPHI  1048576        // spn normalized, bf16 hi [4096][128] ushort (dead after k3)
#define W_SPLO  1310720
#define W_LQU   1572864        // log(q_u) [8192][64] (dead after k3)
#define W_LQB   2097152        // log(q_b) [8192][64] (dead after k3)
#define W_BIAS  2621440        // 0.5*usage_n + 0.5*conf_n [4096] (dead after k3)
#define W_CONFN 2625536        // conf_n [4096] (dead after k3b)
#define W_VALID 2629632        // validity [4096] (dead after k3)
#define W_PSUM  2633728        // per-colblock row partials [32][8192] (dead after k3b)
#define W_PMAX  2895872
#define W_PSIG  3158016
#define W_PUV   3420160
#define W_RINV  3682304        // 1/rowsum [8192] (dead after k3c)
#define W_PTHI  3690496        // proto split bf16 hi, [384 n][4096 k] ushort (live through k4)
#define W_PTLO  4476928
// total ws usage: 5263360 floats = 21.1 MB

typedef __attribute__((ext_vector_type(8))) short short8;
typedef __attribute__((ext_vector_type(4))) float floatx4;

__device__ __forceinline__ unsigned short f2bf(float x) {
    unsigned u = __builtin_bit_cast(unsigned, x);
    u = u + 0x7fffu + ((u >> 16) & 1u);          // round-to-nearest-even
    return (unsigned short)(u >> 16);
}
__device__ __forceinline__ float bf2f(unsigned short h) {
    unsigned u = ((unsigned)h) << 16;
    return __builtin_bit_cast(float, u);
}

// async global->LDS DMA, 16B per lane. LDS dest must be wave-uniform base;
// global src is per-lane.
__device__ __forceinline__ void gload_lds16(const void* g, void* l) {
    __builtin_amdgcn_global_load_lds(
        (const __attribute__((address_space(1))) unsigned*)g,
        (__attribute__((address_space(3))) unsigned*)l, 16, 0, 0);
}

// ---------------------------------------------------------------------------
// K1: global maxes over write_mass/ema_conf -> bias/conf/valid tables.
// ---------------------------------------------------------------------------
__global__ void k1_tables(const float* __restrict__ wm,
                          const float* __restrict__ ec,
                          float* __restrict__ ws)
{
    __shared__ float red1[256];
    __shared__ float red2[256];
    const int tid = threadIdx.x;
    float m1 = 0.0f, m2 = 0.0f;
    for (int i = tid; i < UV; i += 256) {
        m1 = fmaxf(m1, log1pf(wm[i]));
        m2 = fmaxf(m2, ec[i]);
    }
    red1[tid] = m1; red2[tid] = m2;
    __syncthreads();
    for (int s = 128; s > 0; s >>= 1) {
        if (tid < s) {
            red1[tid] = fmaxf(red1[tid], red1[tid + s]);
            red2[tid] = fmaxf(red2[tid], red2[tid + s]);
        }
        __syncthreads();
    }
    const float inv1 = 1.0f / fmaxf(red1[0], 1.0f);
    const float inv2 = 1.0f / fmaxf(red2[0], 1e-6f);
    for (int i = tid; i < UV; i += 256) {
        float w  = wm[i];
        float un = log1pf(w) * inv1;
        float cn = ec[i] * inv2;
        ws[W_BIAS  + i] = 0.5f * un + 0.5f * cn;
        ws[W_CONFN + i] = cn;
        ws[W_VALID + i] = (w > 0.0f) ? 1.0f : 0.0f;
    }
}

// ---------------------------------------------------------------------------
// K2: l2-normalize signature_proto(+1e-6) and q_sigma rows; emit bf16 hi/lo.
// ---------------------------------------------------------------------------
__global__ void k2_norm(const float* __restrict__ spr,
                        const float* __restrict__ qsig,
                        float* __restrict__ ws)
{
    const int wid  = blockIdx.x * 4 + (threadIdx.x >> 6);   // 0..12287
    const int lane = threadIdx.x & 63;
    if (wid < UV) {
        const float* src = spr + (size_t)wid * SDIM;
        float a = src[lane] + 1e-6f;
        float b = src[lane + 64] + 1e-6f;
        float ss = a * a + b * b;
        for (int m = 32; m > 0; m >>= 1) ss += __shfl_xor(ss, m);
        float inv = 1.0f / fmaxf(sqrtf(ss), 1e-12f);
        a *= inv; b *= inv;
        unsigned short* hi = (unsigned short*)(ws + W_SPHI);
        unsigned short* lo = (unsigned short*)(ws + W_SPLO);
        unsigned short ha = f2bf(a), hb = f2bf(b);
        hi[wid * 128 + lane]      = ha;
        hi[wid * 128 + lane + 64] = hb;
        lo[wid * 128 + lane]      = f2bf(a - bf2f(ha));
        lo[wid * 128 + lane + 64] = f2bf(b - bf2f(hb));
    } else {
        const int row = wid - UV;
        const float* src = qsig + (size_t)row * SDIM;
        float a = src[lane];
        float b = src[lane + 64];
        float ss = a * a + b * b;
        for (int m = 32; m > 0; m >>= 1) ss += __shfl_xor(ss, m);
        float inv = 1.0f / fmaxf(sqrtf(ss), 1e-12f);
        a *= inv; b *= inv;
        unsigned short* hi = (unsigned short*)(ws + W_QSHI);
        unsigned short* lo = (unsigned short*)(ws + W_QSLO);
        unsigned short ha = f2bf(a), hb = f2bf(b);
        hi[row * 128 + lane]      = ha;
        hi[row * 128 + lane + 64] = hb;
        lo[row * 128 + lane]      = f2bf(a - bf2f(ha));
        lo[row * 128 + lane + 64] = f2bf(b - bf2f(hb));
    }
}

// ---------------------------------------------------------------------------
// K2b: transpose protos into [n][k] layout and split into bf16 hi/lo pairs.
// ---------------------------------------------------------------------------
__global__ __launch_bounds__(256)
void k2b_protoT(const float* __restrict__ drp, const float* __restrict__ spr,
                float* __restrict__ ws)
{
    __shared__ float tile[32][33];
    const int tid = threadIdx.x;
    const int k0 = blockIdx.x * 32;
    const int n0 = blockIdx.y * 32;
    {
        const int kr = tid >> 3, nc = (tid & 7) * 4;
        const int n = n0 + nc;
        float4 v;
        if (n < 256) v = *(const float4*)&drp[(size_t)(k0 + kr) * 256 + n];
        else         v = *(const float4*)&spr[(size_t)(k0 + kr) * 128 + (n - 256)];
        tile[kr][nc] = v.x; tile[kr][nc + 1] = v.y;
        tile[kr][nc + 2] = v.z; tile[kr][nc + 3] = v.w;
    }
    __syncthreads();
    {
        const int nr = tid >> 3, kc = (tid & 7) * 4;
        unsigned short* pth = (unsigned short*)(ws + W_PTHI);
        unsigned short* ptl = (unsigned short*)(ws + W_PTLO);
        ushort4 h, l;
        float x;
        x = tile[kc + 0][nr]; h.x = f2bf(x); l.x = f2bf(x - bf2f(h.x));
        x = tile[kc + 1][nr]; h.y = f2bf(x); l.y = f2bf(x - bf2f(h.y));
        x = tile[kc + 2][nr]; h.z = f2bf(x); l.z = f2bf(x - bf2f(h.z));
        x = tile[kc + 3][nr]; h.w = f2bf(x); l.w = f2bf(x - bf2f(h.w));
        *(ushort4*)&pth[(size_t)(n0 + nr) * 4096 + k0 + kc] = h;
        *(ushort4*)&ptl[(size_t)(n0 + nr) * 4096 + k0 + kc] = l;
    }
}

// ---------------------------------------------------------------------------
// K2c: log tables for q_u / q_b: lqu[row][64], lqb[row][64].
// ---------------------------------------------------------------------------
__global__ __launch_bounds__(256)
void k2c_logs(const float* __restrict__ qu, const float* __restrict__ qb,
              float* __restrict__ ws)
{
    const int t = blockIdx.x * 256 + threadIdx.x;           // 512 blocks
    const float* src = blockIdx.y ? qb : qu;
    float* dst = ws + (blockIdx.y ? W_LQB : W_LQU);
    float4 v = *(const float4*)&src[t * 4];
    v.x = __logf(v.x); v.y = __logf(v.y);
    v.z = __logf(v.z); v.w = __logf(v.w);
    *(float4*)&dst[t * 4] = v;
}

// ---------------------------------------------------------------------------
// K3: MFMA GEMM1 (qs . spn^T, 3-term bf16 split) fused with logits + exp +
// per-row partial stats. BM=64 BN=128 BK=32 (K=128, 4 chunks), 256 threads
// (2x2 waves), grid (128 row-tiles, 32 col-blocks). Term-major MFMA order.
// ---------------------------------------------------------------------------
#define SA3 40

__global__ __launch_bounds__(256, 4)
void k3_mfma(float* __restrict__ ws, float* __restrict__ dout)
{
    __shared__ unsigned short sAh[64 * SA3];
    __shared__ unsigned short sAl[64 * SA3];
    __shared__ unsigned short sBh[128 * SA3];
    __shared__ unsigned short sBl[128 * SA3];
    __shared__ float sS[2][64], sM[2][64], sG[2][64], sU[2][64];

    const int tid  = threadIdx.x;
    const int row0 = blockIdx.x * 64;
    const int cb   = blockIdx.y;
    const int n0   = cb * 128;

    const unsigned short* qsh = (const unsigned short*)(ws + W_QSHI);
    const unsigned short* qsl = (const unsigned short*)(ws + W_QSLO);
    const unsigned short* sph = (const unsigned short*)(ws + W_SPHI);
    const unsigned short* spl = (const unsigned short*)(ws + W_SPLO);

    const int tAr = tid >> 2;
    const int tAk = (tid & 3) * 8;
    const int tBn = tid >> 2;
    const int tBk = (tid & 3) * 8;

    uint4 pah, pal, pbh[2], pbl[2];
    {
        pah = *(const uint4*)&qsh[(size_t)(row0 + tAr) * 128 + tAk];
        pal = *(const uint4*)&qsl[(size_t)(row0 + tAr) * 128 + tAk];
        #pragma unroll
        for (int p = 0; p < 2; ++p) {
            pbh[p] = *(const uint4*)&sph[(size_t)(n0 + tBn + p * 64) * 128 + tBk];
            pbl[p] = *(const uint4*)&spl[(size_t)(n0 + tBn + p * 64) * 128 + tBk];
        }
    }

    const int lane = tid & 63;
    const int wid  = tid >> 6;
    const int wm   = wid & 1;
    const int wn   = wid >> 1;
    const int fr   = lane & 15;
    const int fq   = lane >> 4;
    const int ako  = fq * 8;

    floatx4 acc[2][4];
    #pragma unroll
    for (int mt = 0; mt < 2; ++mt)
        #pragma unroll
        for (int nt = 0; nt < 4; ++nt)
            acc[mt][nt] = (floatx4){0.f, 0.f, 0.f, 0.f};

    for (int kc = 0; kc < 4; ++kc) {
        __syncthreads();
        *(uint4*)&sAh[tAr * SA3 + tAk] = pah;
        *(uint4*)&sAl[tAr * SA3 + tAk] = pal;
        #pragma unroll
        for (int p = 0; p < 2; ++p) {
            *(uint4*)&sBh[(tBn + p * 64) * SA3 + tBk] = pbh[p];
            *(uint4*)&sBl[(tBn + p * 64) * SA3 + tBk] = pbl[p];
        }
        __syncthreads();

        if (kc < 3) {
            const int kn = (kc + 1) * 32;
            pah = *(const uint4*)&qsh[(size_t)(row0 + tAr) * 128 + kn + tAk];
            pal = *(const uint4*)&qsl[(size_t)(row0 + tAr) * 128 + kn + tAk];
            #pragma unroll
            for (int p = 0; p < 2; ++p) {
                pbh[p] = *(const uint4*)&sph[(size_t)(n0 + tBn + p * 64) * 128 + kn + tBk];
                pbl[p] = *(const uint4*)&spl[(size_t)(n0 + tBn + p * 64) * 128 + kn + tBk];
            }
        }

        short8 afh[2], afl[2], bfh[4], bfl[4];
        #pragma unroll
        for (int mt = 0; mt < 2; ++mt) {
            const int m = wm * 32 + mt * 16 + fr;
            afh[mt] = *(const short8*)&sAh[m * SA3 + ako];
            afl[mt] = *(const short8*)&sAl[m * SA3 + ako];
        }
        #pragma unroll
        for (int nt = 0; nt < 4; ++nt) {
            const int n = wn * 64 + nt * 16 + fr;
            bfh[nt] = *(const short8*)&sBh[n * SA3 + ako];
            bfl[nt] = *(const short8*)&sBl[n * SA3 + ako];
        }
        // term-major: 8 independent MFMAs back-to-back per term
        #pragma unroll
        for (int mt = 0; mt < 2; ++mt)
            #pragma unroll
            for (int nt = 0; nt < 4; ++nt)
                acc[mt][nt] = __builtin_amdgcn_mfma_f32_16x16x32_bf16(
                    afh[mt], bfh[nt], acc[mt][nt], 0, 0, 0);
        #pragma unroll
        for (int mt = 0; mt < 2; ++mt)
            #pragma unroll
            for (int nt = 0; nt < 4; ++nt)
                acc[mt][nt] = __builtin_amdgcn_mfma_f32_16x16x32_bf16(
                    afh[mt], bfl[nt], acc[mt][nt], 0, 0, 0);
        #pragma unroll
        for (int mt = 0; mt < 2; ++mt)
            #pragma unroll
            for (int nt = 0; nt < 4; ++nt)
                acc[mt][nt] = __builtin_amdgcn_mfma_f32_16x16x32_bf16(
                    afl[mt], bfh[nt], acc[mt][nt], 0, 0, 0);
    }

    // --- epilogue: logits -> e (unnormalized), partial row stats -----------
    const float* lqu    = ws + W_LQU;
    const float* lqb    = ws + W_LQB;
    const float* bias   = ws + W_BIAS;
    const float* validf = ws + W_VALID;
    float* wout = dout + O_W;

    float ps[2][4], pm[2][4], pg[2][4], pu[2][4];
    #pragma unroll
    for (int mt = 0; mt < 2; ++mt)
        #pragma unroll
        for (int r = 0; r < 4; ++r) {
            ps[mt][r] = 0.f; pm[mt][r] = -1e30f; pg[mt][r] = 0.f; pu[mt][r] = 0.f;
        }

    #pragma unroll
    for (int mt = 0; mt < 2; ++mt) {
        const int rbase = row0 + wm * 32 + mt * 16 + fq * 4;
        #pragma unroll
        for (int nt = 0; nt < 4; ++nt) {
            const int uvb = n0 + wn * 64 + nt * 16;
            const int u   = uvb >> 6;
            const int uv  = uvb + fr;
            const int v   = uv & 63;
            const float bv = bias[uv];
            const float vd = validf[uv];
            const floatx4 a = acc[mt][nt];
            #pragma unroll
            for (int reg = 0; reg < 4; ++reg) {
                const int row = rbase + reg;
                const float jl  = fmaxf(lqu[(row << 6) + u] + lqb[(row << 6) + v], LOG1EM6);
                const float sig = fmaf(0.5f, a[reg], 0.5f);
                const float lg  = jl + bv + sig;
                const float e   = (vd > 0.f) ? __expf(lg - 2.f) : 0.f;
                wout[((size_t)row << 12) + uv] = e;
                ps[mt][reg] += e;
                if (vd > 0.f && lg > pm[mt][reg]) {
                    pm[mt][reg] = lg; pu[mt][reg] = (float)uv; pg[mt][reg] = sig;
                }
            }
        }
    }

    #pragma unroll
    for (int off = 1; off < 16; off <<= 1) {
        #pragma unroll
        for (int mt = 0; mt < 2; ++mt)
            #pragma unroll
            for (int r = 0; r < 4; ++r) {
                ps[mt][r] += __shfl_xor(ps[mt][r], off);
                float om = __shfl_xor(pm[mt][r], off);
                float ou = __shfl_xor(pu[mt][r], off);
                float og = __shfl_xor(pg[mt][r], off);
                if (om > pm[mt][r] || (om == pm[mt][r] && ou < pu[mt][r])) {
                    pm[mt][r] = om; pu[mt][r] = ou; pg[mt][r] = og;
                }
            }
    }
    if (fr == 0) {
        #pragma unroll
        for (int mt = 0; mt < 2; ++mt)
            #pragma unroll
            for (int r = 0; r < 4; ++r) {
                const int rl = wm * 32 + mt * 16 + fq * 4 + r;
                sS[wn][rl] = ps[mt][r]; sM[wn][rl] = pm[mt][r];
                sG[wn][rl] = pg[mt][r]; sU[wn][rl] = pu[mt][r];
            }
    }
    __syncthreads();
    if (tid < 64) {
        const float s  = sS[0][tid] + sS[1][tid];
        const float m0 = sM[0][tid], m1 = sM[1][tid];
        float m, uvf, g;
        if (m0 > m1 || (m0 == m1 && sU[0][tid] <= sU[1][tid])) {
            m = m0; uvf = sU[0][tid]; g = sG[0][tid];
        } else {
            m = m1; uvf = sU[1][tid]; g = sG[1][tid];
        }
        const int row = row0 + tid;
        ws[W_PSUM + cb * NT + row] = s;
        ws[W_PMAX + cb * NT + row] = m;
        ws[W_PSIG + cb * NT + row] = g;
        ws[W_PUV  + cb * NT + row] = uvf;
    }
}

// ---------------------------------------------------------------------------
// K3b: combine 32 col-block partials per row -> rinv, top_weight, conf.
// ---------------------------------------------------------------------------
__global__ __launch_bounds__(256)
void k3b_stats(float* __restrict__ ws, float* __restrict__ dout)
{
    const int row = blockIdx.x * 256 + threadIdx.x;         // 32 blocks
    float s = 0.f, m = -1e30f, uvf = 0.f, g = 0.f;
    for (int cb = 0; cb < 32; ++cb) {
        s += ws[W_PSUM + cb * NT + row];
        const float om = ws[W_PMAX + cb * NT + row];
        const float ou = ws[W_PUV  + cb * NT + row];
        const float og = ws[W_PSIG + cb * NT + row];
        if (om > m || (om == m && ou < uvf)) { m = om; uvf = ou; g = og; }
    }
    const float inv = 1.0f / s;
    ws[W_RINV + row] = inv;
    const float topw = __expf(m - 2.f) * inv;
    dout[O_TOPW + row] = topw;
    const int uvi = (int)uvf;
    const float cf = topw * ws[W_CONFN + uvi] * g;
    dout[O_CONF + row] = fminf(fmaxf(cf, 0.f), 1.f);
}

// ---------------------------------------------------------------------------
// K3c: normalize weights in place (e -> w), wide grid-strided float4 sweep.
// ---------------------------------------------------------------------------
__global__ __launch_bounds__(256)
void k3c_scale(const float* __restrict__ ws, float* __restrict__ dout)
{
    float4* wb = (float4*)(dout + O_W);
    const float* rinv = ws + W_RINV;
    const int t = blockIdx.x * 256 + threadIdx.x;           // 2048 blocks
    #pragma unroll 4
    for (int i = 0; i < 16; ++i) {
        const int idx = t + i * 524288;
        const float r = rinv[idx >> 10];
        float4 v = wb[idx];
        v.x *= r; v.y *= r; v.z *= r; v.w *= r;
        wb[idx] = v;
    }
}

// ---------------------------------------------------------------------------
// K4: MFMA GEMM2/3, redesigned (round 4).
//   BM=128 BN=192 ksplit=2, grid 256 blocks (1/CU), 512 threads = 8 row-waves,
//   each wave owns a 16x192 output band (mt=1, nt=12, acc=48 VGPR).
//   A (weights, f32): read DIRECTLY from global per lane (each A chunk is
//     consumed by exactly one lane -> no LDS, no staging registers), hi/lo
//     bf16 split in-register.
//   B (protos, bf16 hi/lo): staged via global_load_lds into a double-buffered
//     LDS [2][2][192][32], one barrier per K-step (T3-minimal), with a
//     source-side XOR swizzle (s' = s ^ ((col>>1)&3)) so the ds_read_b128
//     fragment reads are ~2-way-conflict-free (linear layout alone is 8-way).
//   XCD-panel mapping: bid%8 ~ XCD, 2 XCDs pinned per (coltile,ksplit) panel
//     -> each 1.5MB B panel stays L2-resident (kills the ~800MB L3 B-reread
//     traffic that made all previous k4 variants invariant at ~260us).
//   ksplit 0 stores C to dout; ksplit 1 to ws[W_K4P]; k4b adds them.
// ---------------------------------------------------------------------------
__global__ __launch_bounds__(512, 2)
void k4_mfma(float* __restrict__ ws, float* __restrict__ dout)
{
    // [buf][plane][col][kchunk] : 2*2*192*32 ushorts = 48 KB
    __shared__ unsigned short sB[2][2][192 * 32];

    const int tid  = threadIdx.x;
    const int lane = tid & 63;
    const int wv   = tid >> 6;          // 0..7

    // XCD-aware panel decomposition (bijective over 256 blocks)
    const int bid   = blockIdx.x;
    const int xcd   = bid & 7;
    const int panel = xcd >> 1;         // 0..3
    const int ct    = panel & 1;        // coltile
    const int ks    = panel >> 1;       // ksplit
    const int rt    = (bid >> 3) | ((xcd & 1) << 5);   // 0..63

    const int row0 = rt * 128;
    const int n0g  = ct * 192;
    const int kb   = ks * 2048;

    const float* wsrc = dout + O_W;
    const unsigned short* pth = (const unsigned short*)(ws + W_PTHI);
    const unsigned short* ptl = (const unsigned short*)(ws + W_PTLO);

    // B staging: 24 x 1KB wave-chunks per K-step; wave wv owns chunks
    // q = wv*3+j. q<12 -> plane hi at byte q*1024; else plane lo.
    // lane l covers LDS bytes qoff + 16*l: col = q'*16 + (l>>2), slot s'=l&3,
    // source chunk s = s' ^ ((col>>1)&3)  (inverse of the read-side swizzle).
    int st_pl[3], st_ldsoff[3], st_goff[3];
    #pragma unroll
    for (int j = 0; j < 3; ++j) {
        const int q   = wv * 3 + j;
        const int p   = (q >= 12) ? 1 : 0;
        const int qp  = q - p * 12;
        const int col = qp * 16 + (lane >> 2);
        const int s   = (lane & 3) ^ ((col >> 1) & 3);
        st_pl[j]     = p;
        st_ldsoff[j] = qp * 1024;                       // bytes within plane
        st_goff[j]   = (n0g + col) * UV + s * 8;        // ushort offset (+kk)
    }

    const int fr = lane & 15;
    const int fq = lane >> 4;

    // A: lane holds row (row0 + wv*16 + fr), k-chunk fq*8..+8 (f32)
    const float* aptr = wsrc + (size_t)(row0 + wv * 16 + fr) * UV + kb + fq * 8;

    // precomputed swizzled B fragment byte-offsets (iter-invariant)
    int boff[12];
    #pragma unroll
    for (int nt = 0; nt < 12; ++nt) {
        const int col = nt * 16 + fr;
        boff[nt] = col * 32 + ((fq ^ ((col >> 1) & 3)) * 8);   // ushorts
    }

    floatx4 acc[12];
    #pragma unroll
    for (int nt = 0; nt < 12; ++nt)
        acc[nt] = (floatx4){0.f, 0.f, 0.f, 0.f};

    auto stage = [&](int kc_, int buf_) {
        const int kk = kb + kc_ * 32;
        #pragma unroll
        for (int j = 0; j < 3; ++j) {
            const unsigned short* src = (st_pl[j] ? ptl : pth) + st_goff[j] + kk;
            char* dst = (char*)(&sB[buf_][0][0]) + st_pl[j] * 12288 + st_ldsoff[j];
            gload_lds16(src, dst);
        }
    };

    // prologue
    stage(0, 0);
    float4 a0 = *(const float4*)(aptr);
    float4 a1 = *(const float4*)(aptr + 4);
    __syncthreads();                     // drains the DMA (vmcnt 0)

    int buf = 0;
    for (int kc = 0; kc < 64; ++kc) {
        float4 n0 = {}, n1 = {};
        if (kc + 1 < 64) {
            stage(kc + 1, buf ^ 1);      // DMA into other buffer, overlaps MFMA
            n0 = *(const float4*)(aptr + (size_t)(kc + 1) * 32);
            n1 = *(const float4*)(aptr + (size_t)(kc + 1) * 32 + 4);
        }

        // in-register A hi/lo split
        short8 afh, afl;
        {
            const float f[8] = {a0.x, a0.y, a0.z, a0.w, a1.x, a1.y, a1.z, a1.w};
            #pragma unroll
            for (int j = 0; j < 8; ++j) {
                const unsigned short h = f2bf(f[j]);
                afh[j] = (short)h;
                afl[j] = (short)f2bf(f[j] - bf2f(h));
            }
        }

        const unsigned short* bh = &sB[buf][0][0];
        const unsigned short* bl = &sB[buf][1][0];
        #pragma unroll
        for (int nt = 0; nt < 12; ++nt) {
            const short8 bfh = *(const short8*)&bh[boff[nt]];
            const short8 bfl = *(const short8*)&bl[boff[nt]];
            acc[nt] = __builtin_amdgcn_mfma_f32_16x16x32_bf16(afh, bfh, acc[nt], 0, 0, 0);
            acc[nt] = __builtin_amdgcn_mfma_f32_16x16x32_bf16(afh, bfl, acc[nt], 0, 0, 0);
            acc[nt] = __builtin_amdgcn_mfma_f32_16x16x32_bf16(afl, bfh, acc[nt], 0, 0, 0);
        }

        __syncthreads();                 // buf^1 DMA complete; buf free to reuse
        a0 = n0; a1 = n1;
        buf ^= 1;
    }

    // epilogue: plain stores (ks0 -> dout, ks1 -> ws partial)
    const int gr = row0 + wv * 16 + fq * 4;
    #pragma unroll
    for (int nt = 0; nt < 12; ++nt) {
        const int gc = n0g + nt * 16 + fr;
        const floatx4 a = acc[nt];
        if (ks == 0) {
            if (gc < 256) {
                float* o = dout + O_DELTA;
                o[(size_t)(gr + 0) * 256 + gc] = a[0];
                o[(size_t)(gr + 1) * 256 + gc] = a[1];
                o[(size_t)(gr + 2) * 256 + gc] = a[2];
                o[(size_t)(gr + 3) * 256 + gc] = a[3];
            } else {
                float* o = dout + O_SIG;
                const int c = gc - 256;
                o[(size_t)(gr + 0) * 128 + c] = a[0];
                o[(size_t)(gr + 1) * 128 + c] = a[1];
                o[(size_t)(gr + 2) * 128 + c] = a[2];
                o[(size_t)(gr + 3) * 128 + c] = a[3];
            }
        } else {
            float* p = ws + W_K4P;
            p[(size_t)(gr + 0) * 384 + gc] = a[0];
            p[(size_t)(gr + 1) * 384 + gc] = a[1];
            p[(size_t)(gr + 2) * 384 + gc] = a[2];
            p[(size_t)(gr + 3) * 384 + gc] = a[3];
        }
    }
}

// ---------------------------------------------------------------------------
// K4b: dout(delta|sig) += ws partial from ksplit 1. 786432 float4 elements.
// ---------------------------------------------------------------------------
__global__ __launch_bounds__(256)
void k4b_reduce(const float* __restrict__ ws, float* __restrict__ dout)
{
    const int idx = blockIdx.x * 256 + threadIdx.x;         // 3072 blocks
    const int row = idx / 96;                               // 96 float4-cols per row
    const int c   = (idx - row * 96) * 4;
    const float4 p = *(const float4*)&ws[W_K4P + (size_t)row * 384 + c];
    float* dst = (c < 256) ? (dout + O_DELTA + (size_t)row * 256 + c)
                           : (dout + O_SIG   + (size_t)row * 128 + (c - 256));
    float4 d = *(float4*)dst;
    d.x += p.x; d.y += p.y; d.z += p.z; d.w += p.w;
    *(float4*)dst = d;
}

// ---------------------------------------------------------------------------
extern "C" void kernel_launch(void* const* d_in, const int* in_sizes, int n_in,
                              void* d_out, int out_size, void* d_ws, size_t ws_size,
                              hipStream_t stream)
{
    const float* qu   = (const float*)d_in[0];
    const float* qb   = (const float*)d_in[1];
    const float* qsig = (const float*)d_in[2];
    const float* drp  = (const float*)d_in[3];
    const float* spr  = (const float*)d_in[4];
    const float* wm   = (const float*)d_in[5];
    const float* ec   = (const float*)d_in[6];
    float* out = (float*)d_out;
    float* ws  = (float*)d_ws;

    k1_tables<<<1, 256, 0, stream>>>(wm, ec, ws);
    k2_norm<<<3072, 256, 0, stream>>>(spr, qsig, ws);
    k2b_protoT<<<dim3(128, 12), 256, 0, stream>>>(drp, spr, ws);
    k2c_logs<<<dim3(512, 2), 256, 0, stream>>>(qu, qb, ws);
    k3_mfma<<<dim3(128, 32), 256, 0, stream>>>(ws, out);
    k3b_stats<<<32, 256, 0, stream>>>(ws, out);
    k3c_scale<<<2048, 256, 0, stream>>>(ws, out);
    k4_mfma<<<256, 512, 0, stream>>>(ws, out);
    k4b_reduce<<<3072, 256, 0, stream>>>(ws, out);
}

// Round 5
// 432.640 us; speedup vs baseline: 1.3918x; 1.0019x over previous
//
#include <hip/hip_runtime.h>
#include <math.h>

// Problem constants
#define NT   8192          // N*T rows
#define UV   4096          // U*B cells
#define SDIM 128
#define LOG1EM6 -13.815510557964274f

// d_out layout (float offsets): delta[8192][256], sig[8192][128], conf[8192],
// weights[8192][4096], topw[8192]
#define O_DELTA 0
#define O_SIG   2097152
#define O_CONF  3145728
#define O_W     3153920
#define O_TOPW  36708352

// d_ws layout (float offsets)
#define W_K4P   0              // k4 split-1 partial [8192][384] (reuses dead regions below)
#define W_QSHI  0              // qs normalized, bf16 hi [8192][128] ushort (dead after k3)
#define W_QSLO  524288
#define W_SPHI  1048576        // spn normalized, bf16 hi [4096][128] ushort (dead after k3)
#define W_SPLO  1310720
#define W_LQU   1572864        // log(q_u) [8192][64] (dead after k3)
#define W_LQB   2097152        // log(q_b) [8192][64] (dead after k3)
#define W_BIAS  2621440        // 0.5*usage_n + 0.5*conf_n [4096] (dead after k3)
#define W_CONFN 2625536        // conf_n [4096] (dead after k3b)
#define W_VALID 2629632        // validity [4096] (dead after k3)
#define W_PSUM  2633728        // per-colblock row partials [32][8192] (dead after k3b)
#define W_PMAX  2895872
#define W_PSIG  3158016
#define W_PUV   3420160
#define W_RINV  3682304        // 1/rowsum [8192] (dead after k3c)
#define W_PTHI  3690496        // proto split bf16 hi, [384 n][4096 k] ushort (live through k4)
#define W_PTLO  4476928
// total ws usage: 5263360 floats = 21.1 MB

typedef __attribute__((ext_vector_type(8))) short short8;
typedef __attribute__((ext_vector_type(4))) float floatx4;

__device__ __forceinline__ unsigned short f2bf(float x) {
    unsigned u = __builtin_bit_cast(unsigned, x);
    u = u + 0x7fffu + ((u >> 16) & 1u);          // round-to-nearest-even
    return (unsigned short)(u >> 16);
}
__device__ __forceinline__ float bf2f(unsigned short h) {
    unsigned u = ((unsigned)h) << 16;
    return __builtin_bit_cast(float, u);
}

// async global->LDS DMA, 16B per lane. LDS dest must be wave-uniform base;
// global src is per-lane.
__device__ __forceinline__ void gload_lds16(const void* g, void* l) {
    __builtin_amdgcn_global_load_lds(
        (const __attribute__((address_space(1))) unsigned*)g,
        (__attribute__((address_space(3))) unsigned*)l, 16, 0, 0);
}

// ---------------------------------------------------------------------------
// K1: global maxes over write_mass/ema_conf -> bias/conf/valid tables.
// ---------------------------------------------------------------------------
__global__ void k1_tables(const float* __restrict__ wm,
                          const float* __restrict__ ec,
                          float* __restrict__ ws)
{
    __shared__ float red1[256];
    __shared__ float red2[256];
    const int tid = threadIdx.x;
    float m1 = 0.0f, m2 = 0.0f;
    for (int i = tid; i < UV; i += 256) {
        m1 = fmaxf(m1, log1pf(wm[i]));
        m2 = fmaxf(m2, ec[i]);
    }
    red1[tid] = m1; red2[tid] = m2;
    __syncthreads();
    for (int s = 128; s > 0; s >>= 1) {
        if (tid < s) {
            red1[tid] = fmaxf(red1[tid], red1[tid + s]);
            red2[tid] = fmaxf(red2[tid], red2[tid + s]);
        }
        __syncthreads();
    }
    const float inv1 = 1.0f / fmaxf(red1[0], 1.0f);
    const float inv2 = 1.0f / fmaxf(red2[0], 1e-6f);
    for (int i = tid; i < UV; i += 256) {
        float w  = wm[i];
        float un = log1pf(w) * inv1;
        float cn = ec[i] * inv2;
        ws[W_BIAS  + i] = 0.5f * un + 0.5f * cn;
        ws[W_CONFN + i] = cn;
        ws[W_VALID + i] = (w > 0.0f) ? 1.0f : 0.0f;
    }
}

// ---------------------------------------------------------------------------
// K2: l2-normalize signature_proto(+1e-6) and q_sigma rows; emit bf16 hi/lo.
// ---------------------------------------------------------------------------
__global__ void k2_norm(const float* __restrict__ spr,
                        const float* __restrict__ qsig,
                        float* __restrict__ ws)
{
    const int wid  = blockIdx.x * 4 + (threadIdx.x >> 6);   // 0..12287
    const int lane = threadIdx.x & 63;
    if (wid < UV) {
        const float* src = spr + (size_t)wid * SDIM;
        float a = src[lane] + 1e-6f;
        float b = src[lane + 64] + 1e-6f;
        float ss = a * a + b * b;
        for (int m = 32; m > 0; m >>= 1) ss += __shfl_xor(ss, m);
        float inv = 1.0f / fmaxf(sqrtf(ss), 1e-12f);
        a *= inv; b *= inv;
        unsigned short* hi = (unsigned short*)(ws + W_SPHI);
        unsigned short* lo = (unsigned short*)(ws + W_SPLO);
        unsigned short ha = f2bf(a), hb = f2bf(b);
        hi[wid * 128 + lane]      = ha;
        hi[wid * 128 + lane + 64] = hb;
        lo[wid * 128 + lane]      = f2bf(a - bf2f(ha));
        lo[wid * 128 + lane + 64] = f2bf(b - bf2f(hb));
    } else {
        const int row = wid - UV;
        const float* src = qsig + (size_t)row * SDIM;
        float a = src[lane];
        float b = src[lane + 64];
        float ss = a * a + b * b;
        for (int m = 32; m > 0; m >>= 1) ss += __shfl_xor(ss, m);
        float inv = 1.0f / fmaxf(sqrtf(ss), 1e-12f);
        a *= inv; b *= inv;
        unsigned short* hi = (unsigned short*)(ws + W_QSHI);
        unsigned short* lo = (unsigned short*)(ws + W_QSLO);
        unsigned short ha = f2bf(a), hb = f2bf(b);
        hi[row * 128 + lane]      = ha;
        hi[row * 128 + lane + 64] = hb;
        lo[row * 128 + lane]      = f2bf(a - bf2f(ha));
        lo[row * 128 + lane + 64] = f2bf(b - bf2f(hb));
    }
}

// ---------------------------------------------------------------------------
// K2b: transpose protos into [n][k] layout and split into bf16 hi/lo pairs.
// ---------------------------------------------------------------------------
__global__ __launch_bounds__(256)
void k2b_protoT(const float* __restrict__ drp, const float* __restrict__ spr,
                float* __restrict__ ws)
{
    __shared__ float tile[32][33];
    const int tid = threadIdx.x;
    const int k0 = blockIdx.x * 32;
    const int n0 = blockIdx.y * 32;
    {
        const int kr = tid >> 3, nc = (tid & 7) * 4;
        const int n = n0 + nc;
        float4 v;
        if (n < 256) v = *(const float4*)&drp[(size_t)(k0 + kr) * 256 + n];
        else         v = *(const float4*)&spr[(size_t)(k0 + kr) * 128 + (n - 256)];
        tile[kr][nc] = v.x; tile[kr][nc + 1] = v.y;
        tile[kr][nc + 2] = v.z; tile[kr][nc + 3] = v.w;
    }
    __syncthreads();
    {
        const int nr = tid >> 3, kc = (tid & 7) * 4;
        unsigned short* pth = (unsigned short*)(ws + W_PTHI);
        unsigned short* ptl = (unsigned short*)(ws + W_PTLO);
        ushort4 h, l;
        float x;
        x = tile[kc + 0][nr]; h.x = f2bf(x); l.x = f2bf(x - bf2f(h.x));
        x = tile[kc + 1][nr]; h.y = f2bf(x); l.y = f2bf(x - bf2f(h.y));
        x = tile[kc + 2][nr]; h.z = f2bf(x); l.z = f2bf(x - bf2f(h.z));
        x = tile[kc + 3][nr]; h.w = f2bf(x); l.w = f2bf(x - bf2f(h.w));
        *(ushort4*)&pth[(size_t)(n0 + nr) * 4096 + k0 + kc] = h;
        *(ushort4*)&ptl[(size_t)(n0 + nr) * 4096 + k0 + kc] = l;
    }
}

// ---------------------------------------------------------------------------
// K2c: log tables for q_u / q_b: lqu[row][64], lqb[row][64].
// ---------------------------------------------------------------------------
__global__ __launch_bounds__(256)
void k2c_logs(const float* __restrict__ qu, const float* __restrict__ qb,
              float* __restrict__ ws)
{
    const int t = blockIdx.x * 256 + threadIdx.x;           // 512 blocks
    const float* src = blockIdx.y ? qb : qu;
    float* dst = ws + (blockIdx.y ? W_LQB : W_LQU);
    float4 v = *(const float4*)&src[t * 4];
    v.x = __logf(v.x); v.y = __logf(v.y);
    v.z = __logf(v.z); v.w = __logf(v.w);
    *(float4*)&dst[t * 4] = v;
}

// ---------------------------------------------------------------------------
// K3: MFMA GEMM1 (qs . spn^T, 3-term bf16 split) fused with logits + exp +
// per-row partial stats. BM=64 BN=128 BK=32 (K=128, 4 chunks), 256 threads
// (2x2 waves), grid (128 row-tiles, 32 col-blocks). Term-major MFMA order.
// Epilogue v2 (round 5): e values staged into LDS (overlaying the dead
// A/B tiles, slot-XOR swizzle s^=row&7) and written out as per-wave
// 2-row x 512B contiguous float4 stores. Round-4 counters showed the old
// scalar-store epilogue caused 3.2x HBM write amplification (433MB vs
// 138MB logical) and k3 was write-drain bound.
// ---------------------------------------------------------------------------
#define SA3 40

__global__ __launch_bounds__(256, 4)
void k3_mfma(float* __restrict__ ws, float* __restrict__ dout)
{
    // 32 KB: A/B bf16 tiles during the K-loop, overlaid by the f32 e-stage
    // [64 rows][32 f4-slots] in the epilogue.
    __shared__ __align__(16) char smraw[32768];
    unsigned short* sAh = (unsigned short*)smraw;            // 64*SA3
    unsigned short* sAl = sAh + 64 * SA3;
    unsigned short* sBh = sAl + 64 * SA3;                    // 128*SA3
    unsigned short* sBl = sBh + 128 * SA3;
    float* est = (float*)smraw;                              // epilogue overlay
    __shared__ float sS[2][64], sM[2][64], sG[2][64], sU[2][64];

    const int tid  = threadIdx.x;
    const int row0 = blockIdx.x * 64;
    const int cb   = blockIdx.y;
    const int n0   = cb * 128;

    const unsigned short* qsh = (const unsigned short*)(ws + W_QSHI);
    const unsigned short* qsl = (const unsigned short*)(ws + W_QSLO);
    const unsigned short* sph = (const unsigned short*)(ws + W_SPHI);
    const unsigned short* spl = (const unsigned short*)(ws + W_SPLO);

    const int tAr = tid >> 2;
    const int tAk = (tid & 3) * 8;
    const int tBn = tid >> 2;
    const int tBk = (tid & 3) * 8;

    uint4 pah, pal, pbh[2], pbl[2];
    {
        pah = *(const uint4*)&qsh[(size_t)(row0 + tAr) * 128 + tAk];
        pal = *(const uint4*)&qsl[(size_t)(row0 + tAr) * 128 + tAk];
        #pragma unroll
        for (int p = 0; p < 2; ++p) {
            pbh[p] = *(const uint4*)&sph[(size_t)(n0 + tBn + p * 64) * 128 + tBk];
            pbl[p] = *(const uint4*)&spl[(size_t)(n0 + tBn + p * 64) * 128 + tBk];
        }
    }

    const int lane = tid & 63;
    const int wid  = tid >> 6;
    const int wm   = wid & 1;
    const int wn   = wid >> 1;
    const int fr   = lane & 15;
    const int fq   = lane >> 4;
    const int ako  = fq * 8;

    floatx4 acc[2][4];
    #pragma unroll
    for (int mt = 0; mt < 2; ++mt)
        #pragma unroll
        for (int nt = 0; nt < 4; ++nt)
            acc[mt][nt] = (floatx4){0.f, 0.f, 0.f, 0.f};

    for (int kc = 0; kc < 4; ++kc) {
        __syncthreads();
        *(uint4*)&sAh[tAr * SA3 + tAk] = pah;
        *(uint4*)&sAl[tAr * SA3 + tAk] = pal;
        #pragma unroll
        for (int p = 0; p < 2; ++p) {
            *(uint4*)&sBh[(tBn + p * 64) * SA3 + tBk] = pbh[p];
            *(uint4*)&sBl[(tBn + p * 64) * SA3 + tBk] = pbl[p];
        }
        __syncthreads();

        if (kc < 3) {
            const int kn = (kc + 1) * 32;
            pah = *(const uint4*)&qsh[(size_t)(row0 + tAr) * 128 + kn + tAk];
            pal = *(const uint4*)&qsl[(size_t)(row0 + tAr) * 128 + kn + tAk];
            #pragma unroll
            for (int p = 0; p < 2; ++p) {
                pbh[p] = *(const uint4*)&sph[(size_t)(n0 + tBn + p * 64) * 128 + kn + tBk];
                pbl[p] = *(const uint4*)&spl[(size_t)(n0 + tBn + p * 64) * 128 + kn + tBk];
            }
        }

        short8 afh[2], afl[2], bfh[4], bfl[4];
        #pragma unroll
        for (int mt = 0; mt < 2; ++mt) {
            const int m = wm * 32 + mt * 16 + fr;
            afh[mt] = *(const short8*)&sAh[m * SA3 + ako];
            afl[mt] = *(const short8*)&sAl[m * SA3 + ako];
        }
        #pragma unroll
        for (int nt = 0; nt < 4; ++nt) {
            const int n = wn * 64 + nt * 16 + fr;
            bfh[nt] = *(const short8*)&sBh[n * SA3 + ako];
            bfl[nt] = *(const short8*)&sBl[n * SA3 + ako];
        }
        // term-major: 8 independent MFMAs back-to-back per term
        #pragma unroll
        for (int mt = 0; mt < 2; ++mt)
            #pragma unroll
            for (int nt = 0; nt < 4; ++nt)
                acc[mt][nt] = __builtin_amdgcn_mfma_f32_16x16x32_bf16(
                    afh[mt], bfh[nt], acc[mt][nt], 0, 0, 0);
        #pragma unroll
        for (int mt = 0; mt < 2; ++mt)
            #pragma unroll
            for (int nt = 0; nt < 4; ++nt)
                acc[mt][nt] = __builtin_amdgcn_mfma_f32_16x16x32_bf16(
                    afh[mt], bfl[nt], acc[mt][nt], 0, 0, 0);
        #pragma unroll
        for (int mt = 0; mt < 2; ++mt)
            #pragma unroll
            for (int nt = 0; nt < 4; ++nt)
                acc[mt][nt] = __builtin_amdgcn_mfma_f32_16x16x32_bf16(
                    afl[mt], bfh[nt], acc[mt][nt], 0, 0, 0);
    }

    // --- epilogue v2: logits -> e into LDS stage + partial row stats -------
    const float* lqu    = ws + W_LQU;
    const float* lqb    = ws + W_LQB;
    const float* bias   = ws + W_BIAS;
    const float* validf = ws + W_VALID;
    float* wout = dout + O_W;

    float ps[2][4], pm[2][4], pg[2][4], pu[2][4];
    #pragma unroll
    for (int mt = 0; mt < 2; ++mt)
        #pragma unroll
        for (int r = 0; r < 4; ++r) {
            ps[mt][r] = 0.f; pm[mt][r] = -1e30f; pg[mt][r] = 0.f; pu[mt][r] = 0.f;
        }

    __syncthreads();   // all waves done reading sB; reuse LDS as e-stage

    #pragma unroll
    for (int mt = 0; mt < 2; ++mt) {
        const int rl0   = wm * 32 + mt * 16 + fq * 4;       // local row base
        const int rbase = row0 + rl0;
        #pragma unroll
        for (int nt = 0; nt < 4; ++nt) {
            const int uvb = n0 + wn * 64 + nt * 16;
            const int u   = uvb >> 6;
            const int uv  = uvb + fr;
            const int cl  = wn * 64 + nt * 16 + fr;         // local col 0..127
            const int sl  = cl >> 2;                        // f4 slot 0..31
            const int jj  = cl & 3;
            const int v   = uv & 63;
            const float bv = bias[uv];
            const float vd = validf[uv];
            const floatx4 a = acc[mt][nt];
            #pragma unroll
            for (int reg = 0; reg < 4; ++reg) {
                const int row = rbase + reg;
                const int rl  = rl0 + reg;
                const float jl  = fmaxf(lqu[(row << 6) + u] + lqb[(row << 6) + v], LOG1EM6);
                const float sig = fmaf(0.5f, a[reg], 0.5f);
                const float lg  = jl + bv + sig;
                const float e   = (vd > 0.f) ? __expf(lg - 2.f) : 0.f;
                est[(rl << 7) + ((sl ^ (rl & 7)) << 2) + jj] = e;
                ps[mt][reg] += e;
                if (vd > 0.f && lg > pm[mt][reg]) {
                    pm[mt][reg] = lg; pu[mt][reg] = (float)uv; pg[mt][reg] = sig;
                }
            }
        }
    }

    #pragma unroll
    for (int off = 1; off < 16; off <<= 1) {
        #pragma unroll
        for (int mt = 0; mt < 2; ++mt)
            #pragma unroll
            for (int r = 0; r < 4; ++r) {
                ps[mt][r] += __shfl_xor(ps[mt][r], off);
                float om = __shfl_xor(pm[mt][r], off);
                float ou = __shfl_xor(pu[mt][r], off);
                float og = __shfl_xor(pg[mt][r], off);
                if (om > pm[mt][r] || (om == pm[mt][r] && ou < pu[mt][r])) {
                    pm[mt][r] = om; pu[mt][r] = ou; pg[mt][r] = og;
                }
            }
    }
    if (fr == 0) {
        #pragma unroll
        for (int mt = 0; mt < 2; ++mt)
            #pragma unroll
            for (int r = 0; r < 4; ++r) {
                const int rl = wm * 32 + mt * 16 + fq * 4 + r;
                sS[wn][rl] = ps[mt][r]; sM[wn][rl] = pm[mt][r];
                sG[wn][rl] = pg[mt][r]; sU[wn][rl] = pu[mt][r];
            }
    }
    __syncthreads();

    // wide store: each wave writes 2 rows x 512B contiguous per iteration
    #pragma unroll
    for (int i = 0; i < 8; ++i) {
        const int idx = tid + i * 256;
        const int rl  = idx >> 5;                           // 0..63
        const int s   = idx & 31;
        const float4 v = *(const float4*)&est[(rl << 7) + ((s ^ (rl & 7)) << 2)];
        *(float4*)&wout[((size_t)(row0 + rl) << 12) + n0 + s * 4] = v;
    }

    if (tid < 64) {
        const float s  = sS[0][tid] + sS[1][tid];
        const float m0 = sM[0][tid], m1 = sM[1][tid];
        float m, uvf, g;
        if (m0 > m1 || (m0 == m1 && sU[0][tid] <= sU[1][tid])) {
            m = m0; uvf = sU[0][tid]; g = sG[0][tid];
        } else {
            m = m1; uvf = sU[1][tid]; g = sG[1][tid];
        }
        const int row = row0 + tid;
        ws[W_PSUM + cb * NT + row] = s;
        ws[W_PMAX + cb * NT + row] = m;
        ws[W_PSIG + cb * NT + row] = g;
        ws[W_PUV  + cb * NT + row] = uvf;
    }
}

// ---------------------------------------------------------------------------
// K3b: combine 32 col-block partials per row -> rinv, top_weight, conf.
// ---------------------------------------------------------------------------
__global__ __launch_bounds__(256)
void k3b_stats(float* __restrict__ ws, float* __restrict__ dout)
{
    const int row = blockIdx.x * 256 + threadIdx.x;         // 32 blocks
    float s = 0.f, m = -1e30f, uvf = 0.f, g = 0.f;
    for (int cb = 0; cb < 32; ++cb) {
        s += ws[W_PSUM + cb * NT + row];
        const float om = ws[W_PMAX + cb * NT + row];
        const float ou = ws[W_PUV  + cb * NT + row];
        const float og = ws[W_PSIG + cb * NT + row];
        if (om > m || (om == m && ou < uvf)) { m = om; uvf = ou; g = og; }
    }
    const float inv = 1.0f / s;
    ws[W_RINV + row] = inv;
    const float topw = __expf(m - 2.f) * inv;
    dout[O_TOPW + row] = topw;
    const int uvi = (int)uvf;
    const float cf = topw * ws[W_CONFN + uvi] * g;
    dout[O_CONF + row] = fminf(fmaxf(cf, 0.f), 1.f);
}

// ---------------------------------------------------------------------------
// K3c: normalize weights in place (e -> w), wide grid-strided float4 sweep.
// ---------------------------------------------------------------------------
__global__ __launch_bounds__(256)
void k3c_scale(const float* __restrict__ ws, float* __restrict__ dout)
{
    float4* wb = (float4*)(dout + O_W);
    const float* rinv = ws + W_RINV;
    const int t = blockIdx.x * 256 + threadIdx.x;           // 2048 blocks
    #pragma unroll 4
    for (int i = 0; i < 16; ++i) {
        const int idx = t + i * 524288;
        const float r = rinv[idx >> 10];
        float4 v = wb[idx];
        v.x *= r; v.y *= r; v.z *= r; v.w *= r;
        wb[idx] = v;
    }
}

// ---------------------------------------------------------------------------
// K4: MFMA GEMM2/3 (round-4 design, confirmed win).
//   BM=128 BN=192 ksplit=2, grid 256 blocks (1/CU), 512 threads = 8 row-waves,
//   each wave owns a 16x192 output band. A read directly from global per lane
//   (hi/lo split in-register); B staged via global_load_lds into double-
//   buffered LDS with source-side XOR swizzle; XCD-pinned B panels.
// ---------------------------------------------------------------------------
__global__ __launch_bounds__(512, 2)
void k4_mfma(float* __restrict__ ws, float* __restrict__ dout)
{
    // [buf][plane][col][kchunk] : 2*2*192*32 ushorts = 48 KB
    __shared__ unsigned short sB[2][2][192 * 32];

    const int tid  = threadIdx.x;
    const int lane = tid & 63;
    const int wv   = tid >> 6;          // 0..7

    // XCD-aware panel decomposition (bijective over 256 blocks)
    const int bid   = blockIdx.x;
    const int xcd   = bid & 7;
    const int panel = xcd >> 1;         // 0..3
    const int ct    = panel & 1;        // coltile
    const int ks    = panel >> 1;       // ksplit
    const int rt    = (bid >> 3) | ((xcd & 1) << 5);   // 0..63

    const int row0 = rt * 128;
    const int n0g  = ct * 192;
    const int kb   = ks * 2048;

    const float* wsrc = dout + O_W;
    const unsigned short* pth = (const unsigned short*)(ws + W_PTHI);
    const unsigned short* ptl = (const unsigned short*)(ws + W_PTLO);

    int st_pl[3], st_ldsoff[3], st_goff[3];
    #pragma unroll
    for (int j = 0; j < 3; ++j) {
        const int q   = wv * 3 + j;
        const int p   = (q >= 12) ? 1 : 0;
        const int qp  = q - p * 12;
        const int col = qp * 16 + (lane >> 2);
        const int s   = (lane & 3) ^ ((col >> 1) & 3);
        st_pl[j]     = p;
        st_ldsoff[j] = qp * 1024;                       // bytes within plane
        st_goff[j]   = (n0g + col) * UV + s * 8;        // ushort offset (+kk)
    }

    const int fr = lane & 15;
    const int fq = lane >> 4;

    // A: lane holds row (row0 + wv*16 + fr), k-chunk fq*8..+8 (f32)
    const float* aptr = wsrc + (size_t)(row0 + wv * 16 + fr) * UV + kb + fq * 8;

    // precomputed swizzled B fragment byte-offsets (iter-invariant)
    int boff[12];
    #pragma unroll
    for (int nt = 0; nt < 12; ++nt) {
        const int col = nt * 16 + fr;
        boff[nt] = col * 32 + ((fq ^ ((col >> 1) & 3)) * 8);   // ushorts
    }

    floatx4 acc[12];
    #pragma unroll
    for (int nt = 0; nt < 12; ++nt)
        acc[nt] = (floatx4){0.f, 0.f, 0.f, 0.f};

    auto stage = [&](int kc_, int buf_) {
        const int kk = kb + kc_ * 32;
        #pragma unroll
        for (int j = 0; j < 3; ++j) {
            const unsigned short* src = (st_pl[j] ? ptl : pth) + st_goff[j] + kk;
            char* dst = (char*)(&sB[buf_][0][0]) + st_pl[j] * 12288 + st_ldsoff[j];
            gload_lds16(src, dst);
        }
    };

    // prologue
    stage(0, 0);
    float4 a0 = *(const float4*)(aptr);
    float4 a1 = *(const float4*)(aptr + 4);
    __syncthreads();                     // drains the DMA (vmcnt 0)

    int buf = 0;
    for (int kc = 0; kc < 64; ++kc) {
        float4 n0 = {}, n1 = {};
        if (kc + 1 < 64) {
            stage(kc + 1, buf ^ 1);      // DMA into other buffer, overlaps MFMA
            n0 = *(const float4*)(aptr + (size_t)(kc + 1) * 32);
            n1 = *(const float4*)(aptr + (size_t)(kc + 1) * 32 + 4);
        }

        // in-register A hi/lo split
        short8 afh, afl;
        {
            const float f[8] = {a0.x, a0.y, a0.z, a0.w, a1.x, a1.y, a1.z, a1.w};
            #pragma unroll
            for (int j = 0; j < 8; ++j) {
                const unsigned short h = f2bf(f[j]);
                afh[j] = (short)h;
                afl[j] = (short)f2bf(f[j] - bf2f(h));
            }
        }

        const unsigned short* bh = &sB[buf][0][0];
        const unsigned short* bl = &sB[buf][1][0];
        #pragma unroll
        for (int nt = 0; nt < 12; ++nt) {
            const short8 bfh = *(const short8*)&bh[boff[nt]];
            const short8 bfl = *(const short8*)&bl[boff[nt]];
            acc[nt] = __builtin_amdgcn_mfma_f32_16x16x32_bf16(afh, bfh, acc[nt], 0, 0, 0);
            acc[nt] = __builtin_amdgcn_mfma_f32_16x16x32_bf16(afh, bfl, acc[nt], 0, 0, 0);
            acc[nt] = __builtin_amdgcn_mfma_f32_16x16x32_bf16(afl, bfh, acc[nt], 0, 0, 0);
        }

        __syncthreads();                 // buf^1 DMA complete; buf free to reuse
        a0 = n0; a1 = n1;
        buf ^= 1;
    }

    // epilogue: plain stores (ks0 -> dout, ks1 -> ws partial)
    const int gr = row0 + wv * 16 + fq * 4;
    #pragma unroll
    for (int nt = 0; nt < 12; ++nt) {
        const int gc = n0g + nt * 16 + fr;
        const floatx4 a = acc[nt];
        if (ks == 0) {
            if (gc < 256) {
                float* o = dout + O_DELTA;
                o[(size_t)(gr + 0) * 256 + gc] = a[0];
                o[(size_t)(gr + 1) * 256 + gc] = a[1];
                o[(size_t)(gr + 2) * 256 + gc] = a[2];
                o[(size_t)(gr + 3) * 256 + gc] = a[3];
            } else {
                float* o = dout + O_SIG;
                const int c = gc - 256;
                o[(size_t)(gr + 0) * 128 + c] = a[0];
                o[(size_t)(gr + 1) * 128 + c] = a[1];
                o[(size_t)(gr + 2) * 128 + c] = a[2];
                o[(size_t)(gr + 3) * 128 + c] = a[3];
            }
        } else {
            float* p = ws + W_K4P;
            p[(size_t)(gr + 0) * 384 + gc] = a[0];
            p[(size_t)(gr + 1) * 384 + gc] = a[1];
            p[(size_t)(gr + 2) * 384 + gc] = a[2];
            p[(size_t)(gr + 3) * 384 + gc] = a[3];
        }
    }
}

// ---------------------------------------------------------------------------
// K4b: dout(delta|sig) += ws partial from ksplit 1. 786432 float4 elements.
// ---------------------------------------------------------------------------
__global__ __launch_bounds__(256)
void k4b_reduce(const float* __restrict__ ws, float* __restrict__ dout)
{
    const int idx = blockIdx.x * 256 + threadIdx.x;         // 3072 blocks
    const int row = idx / 96;                               // 96 float4-cols per row
    const int c   = (idx - row * 96) * 4;
    const float4 p = *(const float4*)&ws[W_K4P + (size_t)row * 384 + c];
    float* dst = (c < 256) ? (dout + O_DELTA + (size_t)row * 256 + c)
                           : (dout + O_SIG   + (size_t)row * 128 + (c - 256));
    float4 d = *(float4*)dst;
    d.x += p.x; d.y += p.y; d.z += p.z; d.w += p.w;
    *(float4*)dst = d;
}

// ---------------------------------------------------------------------------
extern "C" void kernel_launch(void* const* d_in, const int* in_sizes, int n_in,
                              void* d_out, int out_size, void* d_ws, size_t ws_size,
                              hipStream_t stream)
{
    const float* qu   = (const float*)d_in[0];
    const float* qb   = (const float*)d_in[1];
    const float* qsig = (const float*)d_in[2];
    const float* drp  = (const float*)d_in[3];
    const float* spr  = (const float*)d_in[4];
    const float* wm   = (const float*)d_in[5];
    const float* ec   = (const float*)d_in[6];
    float* out = (float*)d_out;
    float* ws  = (float*)d_ws;

    k1_tables<<<1, 256, 0, stream>>>(wm, ec, ws);
    k2_norm<<<3072, 256, 0, stream>>>(spr, qsig, ws);
    k2b_protoT<<<dim3(128, 12), 256, 0, stream>>>(drp, spr, ws);
    k2c_logs<<<dim3(512, 2), 256, 0, stream>>>(qu, qb, ws);
    k3_mfma<<<dim3(128, 32), 256, 0, stream>>>(ws, out);
    k3b_stats<<<32, 256, 0, stream>>>(ws, out);
    k3c_scale<<<2048, 256, 0, stream>>>(ws, out);
    k4_mfma<<<256, 512, 0, stream>>>(ws, out);
    k4b_reduce<<<3072, 256, 0, stream>>>(ws, out);
}

// Round 6
// 426.374 us; speedup vs baseline: 1.4123x; 1.0147x over previous
//
#include <hip/hip_runtime.h>
#include <math.h>

// Problem constants
#define NT   8192          // N*T rows
#define UV   4096          // U*B cells
#define SDIM 128
#define LOG1EM6 -13.815510557964274f

// d_out layout (float offsets): delta[8192][256], sig[8192][128], conf[8192],
// weights[8192][4096], topw[8192]
#define O_DELTA 0
#define O_SIG   2097152
#define O_CONF  3145728
#define O_W     3153920
#define O_TOPW  36708352

// d_ws layout (float offsets)
#define W_K4P   0              // k4 split-1 partial [8192][384] (reuses dead regions below)
#define W_QSHI  0              // qs normalized, bf16 hi [8192][128] ushort (dead after k3)
#define W_QSLO  524288
#define W_SPHI  1048576        // spn normalized, bf16 hi [4096][128] ushort (dead after k3)
#define W_SPLO  1310720
#define W_LQU   1572864        // log(q_u) [8192][64] (dead after k3)
#define W_LQB   2097152        // log(q_b) [8192][64] (dead after k3)
#define W_BIAS  2621440        // 0.5*usage_n + 0.5*conf_n [4096] (dead after k3)
#define W_CONFN 2625536        // conf_n [4096] (dead after k3b)
#define W_VALID 2629632        // validity [4096] (dead after k3)
#define W_PSUM  2633728        // per-colblock row partials [32][8192] (dead after k3b)
#define W_PMAX  2895872
#define W_PSIG  3158016
#define W_PUV   3420160
#define W_RINV  3682304        // 1/rowsum [8192] (read by k4; OUTSIDE K4P)
#define W_PTHI  3690496        // proto split bf16 hi, [384 n][4096 k] ushort (live through k4)
#define W_PTLO  4476928
// total ws usage: 5263360 floats = 21.1 MB
// K4P [0,3145728) overlays QSHI..PUV: all dead once k3b has consumed the
// stats tables (k3b runs BEFORE k4). W_RINV and W_PT* are outside K4P.

typedef __attribute__((ext_vector_type(8))) short short8;
typedef __attribute__((ext_vector_type(4))) float floatx4;

__device__ __forceinline__ unsigned short f2bf(float x) {
    unsigned u = __builtin_bit_cast(unsigned, x);
    u = u + 0x7fffu + ((u >> 16) & 1u);          // round-to-nearest-even
    return (unsigned short)(u >> 16);
}
__device__ __forceinline__ float bf2f(unsigned short h) {
    unsigned u = ((unsigned)h) << 16;
    return __builtin_bit_cast(float, u);
}

// async global->LDS DMA, 16B per lane. LDS dest must be wave-uniform base
// (HW adds lane*16); global src is per-lane.
__device__ __forceinline__ void gload_lds16(const void* g, void* l) {
    __builtin_amdgcn_global_load_lds(
        (const __attribute__((address_space(1))) unsigned*)g,
        (__attribute__((address_space(3))) unsigned*)l, 16, 0, 0);
}

// ---------------------------------------------------------------------------
// KPREP: fused k1 (tables) + k2 (l2norm) + k2b (protoT) + k2c (logs).
// Grid 5633 blocks x 256 threads, switched on blockIdx ranges. All four
// sub-kernels are mutually independent (disjoint reads/writes).
//   [0,3072)      : k2 norm (wid = bid*4 + tid>>6)
//   [3072,4608)   : k2b protoT (128 k-tiles x 12 n-tiles)
//   [4608,5632)   : k2c logs (512 x 2)
//   5632          : k1 tables (single block)
// ---------------------------------------------------------------------------
__global__ __launch_bounds__(256)
void kprep(const float* __restrict__ qu, const float* __restrict__ qb,
           const float* __restrict__ qsig, const float* __restrict__ drp,
           const float* __restrict__ spr, const float* __restrict__ wm,
           const float* __restrict__ ec, float* __restrict__ ws)
{
    __shared__ float red1[256];
    __shared__ float red2[256];
    __shared__ float tile[32][33];

    const int bid = blockIdx.x;
    const int tid = threadIdx.x;

    if (bid < 3072) {
        // ---- k2: l2-normalize spn(+1e-6) / qs rows; emit bf16 hi/lo ----
        const int wid  = bid * 4 + (tid >> 6);   // 0..12287
        const int lane = tid & 63;
        if (wid < UV) {
            const float* src = spr + (size_t)wid * SDIM;
            float a = src[lane] + 1e-6f;
            float b = src[lane + 64] + 1e-6f;
            float ss = a * a + b * b;
            for (int m = 32; m > 0; m >>= 1) ss += __shfl_xor(ss, m);
            float inv = 1.0f / fmaxf(sqrtf(ss), 1e-12f);
            a *= inv; b *= inv;
            unsigned short* hi = (unsigned short*)(ws + W_SPHI);
            unsigned short* lo = (unsigned short*)(ws + W_SPLO);
            unsigned short ha = f2bf(a), hb = f2bf(b);
            hi[wid * 128 + lane]      = ha;
            hi[wid * 128 + lane + 64] = hb;
            lo[wid * 128 + lane]      = f2bf(a - bf2f(ha));
            lo[wid * 128 + lane + 64] = f2bf(b - bf2f(hb));
        } else {
            const int row = wid - UV;
            const float* src = qsig + (size_t)row * SDIM;
            float a = src[lane];
            float b = src[lane + 64];
            float ss = a * a + b * b;
            for (int m = 32; m > 0; m >>= 1) ss += __shfl_xor(ss, m);
            float inv = 1.0f / fmaxf(sqrtf(ss), 1e-12f);
            a *= inv; b *= inv;
            unsigned short* hi = (unsigned short*)(ws + W_QSHI);
            unsigned short* lo = (unsigned short*)(ws + W_QSLO);
            unsigned short ha = f2bf(a), hb = f2bf(b);
            hi[row * 128 + lane]      = ha;
            hi[row * 128 + lane + 64] = hb;
            lo[row * 128 + lane]      = f2bf(a - bf2f(ha));
            lo[row * 128 + lane + 64] = f2bf(b - bf2f(hb));
        }
    } else if (bid < 4608) {
        // ---- k2b: transpose protos -> [n][k], split bf16 hi/lo ----
        const int sub = bid - 3072;
        const int k0  = (sub & 127) * 32;
        const int n0  = (sub >> 7) * 32;
        {
            const int kr = tid >> 3, nc = (tid & 7) * 4;
            const int n = n0 + nc;
            float4 v;
            if (n < 256) v = *(const float4*)&drp[(size_t)(k0 + kr) * 256 + n];
            else         v = *(const float4*)&spr[(size_t)(k0 + kr) * 128 + (n - 256)];
            tile[kr][nc] = v.x; tile[kr][nc + 1] = v.y;
            tile[kr][nc + 2] = v.z; tile[kr][nc + 3] = v.w;
        }
        __syncthreads();
        {
            const int nr = tid >> 3, kc = (tid & 7) * 4;
            unsigned short* pth = (unsigned short*)(ws + W_PTHI);
            unsigned short* ptl = (unsigned short*)(ws + W_PTLO);
            ushort4 h, l;
            float x;
            x = tile[kc + 0][nr]; h.x = f2bf(x); l.x = f2bf(x - bf2f(h.x));
            x = tile[kc + 1][nr]; h.y = f2bf(x); l.y = f2bf(x - bf2f(h.y));
            x = tile[kc + 2][nr]; h.z = f2bf(x); l.z = f2bf(x - bf2f(h.z));
            x = tile[kc + 3][nr]; h.w = f2bf(x); l.w = f2bf(x - bf2f(h.w));
            *(ushort4*)&pth[(size_t)(n0 + nr) * 4096 + k0 + kc] = h;
            *(ushort4*)&ptl[(size_t)(n0 + nr) * 4096 + k0 + kc] = l;
        }
    } else if (bid < 5632) {
        // ---- k2c: log tables ----
        const int sub = bid - 4608;
        const int t = (sub & 511) * 256 + tid;
        const float* src = (sub >> 9) ? qb : qu;
        float* dst = ws + ((sub >> 9) ? W_LQB : W_LQU);
        float4 v = *(const float4*)&src[t * 4];
        v.x = __logf(v.x); v.y = __logf(v.y);
        v.z = __logf(v.z); v.w = __logf(v.w);
        *(float4*)&dst[t * 4] = v;
    } else {
        // ---- k1: global maxes -> bias/conf/valid tables ----
        float m1 = 0.0f, m2 = 0.0f;
        for (int i = tid; i < UV; i += 256) {
            m1 = fmaxf(m1, log1pf(wm[i]));
            m2 = fmaxf(m2, ec[i]);
        }
        red1[tid] = m1; red2[tid] = m2;
        __syncthreads();
        for (int s = 128; s > 0; s >>= 1) {
            if (tid < s) {
                red1[tid] = fmaxf(red1[tid], red1[tid + s]);
                red2[tid] = fmaxf(red2[tid], red2[tid + s]);
            }
            __syncthreads();
        }
        const float inv1 = 1.0f / fmaxf(red1[0], 1.0f);
        const float inv2 = 1.0f / fmaxf(red2[0], 1e-6f);
        for (int i = tid; i < UV; i += 256) {
            float w  = wm[i];
            float un = log1pf(w) * inv1;
            float cn = ec[i] * inv2;
            ws[W_BIAS  + i] = 0.5f * un + 0.5f * cn;
            ws[W_CONFN + i] = cn;
            ws[W_VALID + i] = (w > 0.0f) ? 1.0f : 0.0f;
        }
    }
}

// ---------------------------------------------------------------------------
// K3: MFMA GEMM1 (qs . spn^T, 3-term bf16 split) fused with logits + exp +
// per-row partial stats. BM=64 BN=128 BK=32 (K=128, 4 chunks), 256 threads
// (2x2 waves), grid (128 row-tiles, 32 col-blocks). Term-major MFMA order.
// (Round-4 epilogue restored: the round-5 LDS-staged wide-store epilogue
// left WRITE_SIZE unchanged and cost 14us.)
// ---------------------------------------------------------------------------
#define SA3 40

__global__ __launch_bounds__(256, 4)
void k3_mfma(float* __restrict__ ws, float* __restrict__ dout)
{
    __shared__ unsigned short sAh[64 * SA3];
    __shared__ unsigned short sAl[64 * SA3];
    __shared__ unsigned short sBh[128 * SA3];
    __shared__ unsigned short sBl[128 * SA3];
    __shared__ float sS[2][64], sM[2][64], sG[2][64], sU[2][64];

    const int tid  = threadIdx.x;
    const int row0 = blockIdx.x * 64;
    const int cb   = blockIdx.y;
    const int n0   = cb * 128;

    const unsigned short* qsh = (const unsigned short*)(ws + W_QSHI);
    const unsigned short* qsl = (const unsigned short*)(ws + W_QSLO);
    const unsigned short* sph = (const unsigned short*)(ws + W_SPHI);
    const unsigned short* spl = (const unsigned short*)(ws + W_SPLO);

    const int tAr = tid >> 2;
    const int tAk = (tid & 3) * 8;
    const int tBn = tid >> 2;
    const int tBk = (tid & 3) * 8;

    uint4 pah, pal, pbh[2], pbl[2];
    {
        pah = *(const uint4*)&qsh[(size_t)(row0 + tAr) * 128 + tAk];
        pal = *(const uint4*)&qsl[(size_t)(row0 + tAr) * 128 + tAk];
        #pragma unroll
        for (int p = 0; p < 2; ++p) {
            pbh[p] = *(const uint4*)&sph[(size_t)(n0 + tBn + p * 64) * 128 + tBk];
            pbl[p] = *(const uint4*)&spl[(size_t)(n0 + tBn + p * 64) * 128 + tBk];
        }
    }

    const int lane = tid & 63;
    const int wid  = tid >> 6;
    const int wm   = wid & 1;
    const int wn   = wid >> 1;
    const int fr   = lane & 15;
    const int fq   = lane >> 4;
    const int ako  = fq * 8;

    floatx4 acc[2][4];
    #pragma unroll
    for (int mt = 0; mt < 2; ++mt)
        #pragma unroll
        for (int nt = 0; nt < 4; ++nt)
            acc[mt][nt] = (floatx4){0.f, 0.f, 0.f, 0.f};

    for (int kc = 0; kc < 4; ++kc) {
        __syncthreads();
        *(uint4*)&sAh[tAr * SA3 + tAk] = pah;
        *(uint4*)&sAl[tAr * SA3 + tAk] = pal;
        #pragma unroll
        for (int p = 0; p < 2; ++p) {
            *(uint4*)&sBh[(tBn + p * 64) * SA3 + tBk] = pbh[p];
            *(uint4*)&sBl[(tBn + p * 64) * SA3 + tBk] = pbl[p];
        }
        __syncthreads();

        if (kc < 3) {
            const int kn = (kc + 1) * 32;
            pah = *(const uint4*)&qsh[(size_t)(row0 + tAr) * 128 + kn + tAk];
            pal = *(const uint4*)&qsl[(size_t)(row0 + tAr) * 128 + kn + tAk];
            #pragma unroll
            for (int p = 0; p < 2; ++p) {
                pbh[p] = *(const uint4*)&sph[(size_t)(n0 + tBn + p * 64) * 128 + kn + tBk];
                pbl[p] = *(const uint4*)&spl[(size_t)(n0 + tBn + p * 64) * 128 + kn + tBk];
            }
        }

        short8 afh[2], afl[2], bfh[4], bfl[4];
        #pragma unroll
        for (int mt = 0; mt < 2; ++mt) {
            const int m = wm * 32 + mt * 16 + fr;
            afh[mt] = *(const short8*)&sAh[m * SA3 + ako];
            afl[mt] = *(const short8*)&sAl[m * SA3 + ako];
        }
        #pragma unroll
        for (int nt = 0; nt < 4; ++nt) {
            const int n = wn * 64 + nt * 16 + fr;
            bfh[nt] = *(const short8*)&sBh[n * SA3 + ako];
            bfl[nt] = *(const short8*)&sBl[n * SA3 + ako];
        }
        // term-major: 8 independent MFMAs back-to-back per term
        #pragma unroll
        for (int mt = 0; mt < 2; ++mt)
            #pragma unroll
            for (int nt = 0; nt < 4; ++nt)
                acc[mt][nt] = __builtin_amdgcn_mfma_f32_16x16x32_bf16(
                    afh[mt], bfh[nt], acc[mt][nt], 0, 0, 0);
        #pragma unroll
        for (int mt = 0; mt < 2; ++mt)
            #pragma unroll
            for (int nt = 0; nt < 4; ++nt)
                acc[mt][nt] = __builtin_amdgcn_mfma_f32_16x16x32_bf16(
                    afh[mt], bfl[nt], acc[mt][nt], 0, 0, 0);
        #pragma unroll
        for (int mt = 0; mt < 2; ++mt)
            #pragma unroll
            for (int nt = 0; nt < 4; ++nt)
                acc[mt][nt] = __builtin_amdgcn_mfma_f32_16x16x32_bf16(
                    afl[mt], bfh[nt], acc[mt][nt], 0, 0, 0);
    }

    // --- epilogue: logits -> e (unnormalized), partial row stats -----------
    const float* lqu    = ws + W_LQU;
    const float* lqb    = ws + W_LQB;
    const float* bias   = ws + W_BIAS;
    const float* validf = ws + W_VALID;
    float* wout = dout + O_W;

    float ps[2][4], pm[2][4], pg[2][4], pu[2][4];
    #pragma unroll
    for (int mt = 0; mt < 2; ++mt)
        #pragma unroll
        for (int r = 0; r < 4; ++r) {
            ps[mt][r] = 0.f; pm[mt][r] = -1e30f; pg[mt][r] = 0.f; pu[mt][r] = 0.f;
        }

    #pragma unroll
    for (int mt = 0; mt < 2; ++mt) {
        const int rbase = row0 + wm * 32 + mt * 16 + fq * 4;
        #pragma unroll
        for (int nt = 0; nt < 4; ++nt) {
            const int uvb = n0 + wn * 64 + nt * 16;
            const int u   = uvb >> 6;
            const int uv  = uvb + fr;
            const int v   = uv & 63;
            const float bv = bias[uv];
            const float vd = validf[uv];
            const floatx4 a = acc[mt][nt];
            #pragma unroll
            for (int reg = 0; reg < 4; ++reg) {
                const int row = rbase + reg;
                const float jl  = fmaxf(lqu[(row << 6) + u] + lqb[(row << 6) + v], LOG1EM6);
                const float sig = fmaf(0.5f, a[reg], 0.5f);
                const float lg  = jl + bv + sig;
                const float e   = (vd > 0.f) ? __expf(lg - 2.f) : 0.f;
                wout[((size_t)row << 12) + uv] = e;
                ps[mt][reg] += e;
                if (vd > 0.f && lg > pm[mt][reg]) {
                    pm[mt][reg] = lg; pu[mt][reg] = (float)uv; pg[mt][reg] = sig;
                }
            }
        }
    }

    #pragma unroll
    for (int off = 1; off < 16; off <<= 1) {
        #pragma unroll
        for (int mt = 0; mt < 2; ++mt)
            #pragma unroll
            for (int r = 0; r < 4; ++r) {
                ps[mt][r] += __shfl_xor(ps[mt][r], off);
                float om = __shfl_xor(pm[mt][r], off);
                float ou = __shfl_xor(pu[mt][r], off);
                float og = __shfl_xor(pg[mt][r], off);
                if (om > pm[mt][r] || (om == pm[mt][r] && ou < pu[mt][r])) {
                    pm[mt][r] = om; pu[mt][r] = ou; pg[mt][r] = og;
                }
            }
    }
    if (fr == 0) {
        #pragma unroll
        for (int mt = 0; mt < 2; ++mt)
            #pragma unroll
            for (int r = 0; r < 4; ++r) {
                const int rl = wm * 32 + mt * 16 + fq * 4 + r;
                sS[wn][rl] = ps[mt][r]; sM[wn][rl] = pm[mt][r];
                sG[wn][rl] = pg[mt][r]; sU[wn][rl] = pu[mt][r];
            }
    }
    __syncthreads();
    if (tid < 64) {
        const float s  = sS[0][tid] + sS[1][tid];
        const float m0 = sM[0][tid], m1 = sM[1][tid];
        float m, uvf, g;
        if (m0 > m1 || (m0 == m1 && sU[0][tid] <= sU[1][tid])) {
            m = m0; uvf = sU[0][tid]; g = sG[0][tid];
        } else {
            m = m1; uvf = sU[1][tid]; g = sG[1][tid];
        }
        const int row = row0 + tid;
        ws[W_PSUM + cb * NT + row] = s;
        ws[W_PMAX + cb * NT + row] = m;
        ws[W_PSIG + cb * NT + row] = g;
        ws[W_PUV  + cb * NT + row] = uvf;
    }
}

// ---------------------------------------------------------------------------
// K3b: combine 32 col-block partials per row -> rinv, top_weight, conf.
// Kept as a separate dispatch: it DRAINS the stats tables (which k4's
// K4P partial region overlays) and publishes rinv for k4.
// ---------------------------------------------------------------------------
__global__ __launch_bounds__(256)
void k3b_stats(float* __restrict__ ws, float* __restrict__ dout)
{
    const int row = blockIdx.x * 256 + threadIdx.x;         // 32 blocks
    float s = 0.f, m = -1e30f, uvf = 0.f, g = 0.f;
    for (int cb = 0; cb < 32; ++cb) {
        s += ws[W_PSUM + cb * NT + row];
        const float om = ws[W_PMAX + cb * NT + row];
        const float ou = ws[W_PUV  + cb * NT + row];
        const float og = ws[W_PSIG + cb * NT + row];
        if (om > m || (om == m && ou < uvf)) { m = om; uvf = ou; g = og; }
    }
    const float inv = 1.0f / s;
    ws[W_RINV + row] = inv;
    const float topw = __expf(m - 2.f) * inv;
    dout[O_TOPW + row] = topw;
    const int uvi = (int)uvf;
    const float cf = topw * ws[W_CONFN + uvi] * g;
    dout[O_CONF + row] = fminf(fmaxf(cf, 0.f), 1.f);
}

// ---------------------------------------------------------------------------
// K4: MFMA GEMM2/3 + fused weight normalization (k3c eliminated).
//   BM=64, BN=384 (full width), ksplit=2 -> grid 256 blocks (1/CU),
//   512 threads = 8 waves (wm=wv&3: 16-row band; wn=wv>>2: 192-col half).
//   A = RAW e from dout O_W, per-lane direct loads, bf16 hi/lo split
//   in-register; accumulator scaled by rinv[row] in the epilogue
//   (delta = rinv * sum(e*P) == sum(w*P)).
//   Normalized weights w = e*rinv are written back IN PLACE by wn==0 waves
//   with a lag-1 schedule (write chunk kc-1 during interval kc): the only
//   other reader of those elements is the paired wave in the SAME block,
//   whose read of chunk kc-1 completed before the barrier ending interval
//   kc-1. Across blocks each (row, k-half) belongs to exactly one block.
//   B staged via global_load_lds, double-buffered, 4-slot XOR swizzle
//   (2-way conflict on ds_read_b128 = free). XCD-pinned: XCDs 0-3 cache the
//   ks0 B-half (3MB), XCDs 4-7 the ks1 half.
//   ks0 stores C direct to dout; ks1 to ws[W_K4P]; k4b adds them.
// ---------------------------------------------------------------------------
__global__ __launch_bounds__(512, 1)
void k4_mfma(float* __restrict__ ws, float* __restrict__ dout)
{
    // [buf][plane][col*32 kslots] : 2*2*12288 ushorts = 96 KB
    __shared__ unsigned short sB[2][2][12288];

    const int tid  = threadIdx.x;
    const int lane = tid & 63;
    const int wv   = tid >> 6;          // 0..7

    // bijective XCD mapping: xcd = bid&7; ks pinned per XCD-half
    const int bid = blockIdx.x;
    const int xcd = bid & 7;
    const int ks  = xcd >> 2;                            // 0..1
    const int rt  = ((bid >> 3) << 2) | (xcd & 3);       // 0..127
    const int row0 = rt * 64;
    const int kb   = ks * 2048;

    const unsigned short* pth = (const unsigned short*)(ws + W_PTHI);
    const unsigned short* ptl = (const unsigned short*)(ws + W_PTLO);

    // B staging: 3072 16B chunks per K-step (2 planes x 384 cols x 4 slots);
    // 6 chunks per thread. LDS base is wave-uniform (HW adds lane*16).
    int st_pl[6], st_ubase[6], st_goff[6];
    #pragma unroll
    for (int j = 0; j < 6; ++j) {
        const int cu = (tid & ~63) + j * 512;            // wave-uniform chunk base
        const int c  = cu + lane;                        // this lane's chunk
        const int pl = (cu >= 1536) ? 1 : 0;
        const int cc = c - pl * 1536;                    // 0..1535
        const int col = cc >> 2;                         // 0..383
        const int sl  = (cc & 3) ^ ((col >> 1) & 3);     // source slot (involution)
        st_pl[j]    = pl;
        st_ubase[j] = pl * 24576 + (cu - pl * 1536) * 16; // bytes from sB[buf]
        st_goff[j]  = col * UV + sl * 8;                 // ushort offset (+k)
    }

    const int fr = lane & 15;
    const int fq = lane >> 4;            // 0..3

    const int wm = wv & 3;               // 16-row band
    const int wn = wv >> 2;              // 192-col half

    // A: lane owns row (row0 + wm*16 + fr), k-chunk fq*8 (+kc*32), raw e f32
    const int arow = row0 + wm * 16 + fr;
    const float* aptr = dout + O_W + (size_t)arow * UV + kb + fq * 8;
    float*       awb  = dout + O_W + (size_t)arow * UV + kb + fq * 8;
    const float rinv_a = ws[W_RINV + arow];

    // swizzled B fragment offsets (ushorts within a plane)
    int boff[12];
    #pragma unroll
    for (int nt = 0; nt < 12; ++nt) {
        const int col = wn * 192 + nt * 16 + fr;
        boff[nt] = col * 32 + ((fq ^ ((col >> 1) & 3)) * 8);
    }

    floatx4 acc[12];
    #pragma unroll
    for (int nt = 0; nt < 12; ++nt)
        acc[nt] = (floatx4){0.f, 0.f, 0.f, 0.f};

    auto stage = [&](int kc_, int buf_) {
        const int kk = kb + kc_ * 32;
        #pragma unroll
        for (int j = 0; j < 6; ++j) {
            const unsigned short* src = (st_pl[j] ? ptl : pth) + st_goff[j] + kk;
            char* dst = (char*)(&sB[buf_][0][0]) + st_ubase[j];
            gload_lds16(src, dst);
        }
    };

    // prologue
    stage(0, 0);
    float4 a0 = *(const float4*)(aptr);
    float4 a1 = *(const float4*)(aptr + 4);
    __syncthreads();                     // drains DMA

    float4 p0 = {}, p1 = {};
    int buf = 0;
    for (int kc = 0; kc < 64; ++kc) {
        float4 n0 = {}, n1 = {};
        if (kc + 1 < 64) {
            stage(kc + 1, buf ^ 1);      // DMA into other buffer, overlaps MFMA
            n0 = *(const float4*)(aptr + (size_t)(kc + 1) * 32);
            n1 = *(const float4*)(aptr + (size_t)(kc + 1) * 32 + 4);
        }

        // lag-1 normalized-weight writeback (wn==0 waves cover all rows/k)
        if (wn == 0 && kc > 0) {
            float4 w0, w1;
            w0.x = p0.x * rinv_a; w0.y = p0.y * rinv_a;
            w0.z = p0.z * rinv_a; w0.w = p0.w * rinv_a;
            w1.x = p1.x * rinv_a; w1.y = p1.y * rinv_a;
            w1.z = p1.z * rinv_a; w1.w = p1.w * rinv_a;
            *(float4*)(awb + (size_t)(kc - 1) * 32)     = w0;
            *(float4*)(awb + (size_t)(kc - 1) * 32 + 4) = w1;
        }

        // in-register A hi/lo split
        short8 afh, afl;
        {
            const float f[8] = {a0.x, a0.y, a0.z, a0.w, a1.x, a1.y, a1.z, a1.w};
            #pragma unroll
            for (int j = 0; j < 8; ++j) {
                const unsigned short h = f2bf(f[j]);
                afh[j] = (short)h;
                afl[j] = (short)f2bf(f[j] - bf2f(h));
            }
        }

        const unsigned short* bh = &sB[buf][0][0];
        const unsigned short* bl = &sB[buf][1][0];
        #pragma unroll
        for (int nt = 0; nt < 12; ++nt) {
            const short8 bfh = *(const short8*)&bh[boff[nt]];
            const short8 bfl = *(const short8*)&bl[boff[nt]];
            acc[nt] = __builtin_amdgcn_mfma_f32_16x16x32_bf16(afh, bfh, acc[nt], 0, 0, 0);
            acc[nt] = __builtin_amdgcn_mfma_f32_16x16x32_bf16(afh, bfl, acc[nt], 0, 0, 0);
            acc[nt] = __builtin_amdgcn_mfma_f32_16x16x32_bf16(afl, bfh, acc[nt], 0, 0, 0);
        }

        p0 = a0; p1 = a1;
        __syncthreads();                 // buf^1 DMA complete; buf reusable
        a0 = n0; a1 = n1;
        buf ^= 1;
    }
    // tail writeback (chunk 63)
    if (wn == 0) {
        float4 w0, w1;
        w0.x = p0.x * rinv_a; w0.y = p0.y * rinv_a;
        w0.z = p0.z * rinv_a; w0.w = p0.w * rinv_a;
        w1.x = p1.x * rinv_a; w1.y = p1.y * rinv_a;
        w1.z = p1.z * rinv_a; w1.w = p1.w * rinv_a;
        *(float4*)(awb + (size_t)63 * 32)     = w0;
        *(float4*)(awb + (size_t)63 * 32 + 4) = w1;
    }

    // epilogue: scale by rinv, plain stores (ks0 -> dout, ks1 -> ws partial)
    const int gr = row0 + wm * 16 + fq * 4;
    float rv[4];
    #pragma unroll
    for (int r = 0; r < 4; ++r) rv[r] = ws[W_RINV + gr + r];

    #pragma unroll
    for (int nt = 0; nt < 12; ++nt) {
        const int gc = wn * 192 + nt * 16 + fr;
        floatx4 a = acc[nt];
        a[0] *= rv[0]; a[1] *= rv[1]; a[2] *= rv[2]; a[3] *= rv[3];
        if (ks == 0) {
            if (gc < 256) {
                float* o = dout + O_DELTA;
                o[(size_t)(gr + 0) * 256 + gc] = a[0];
                o[(size_t)(gr + 1) * 256 + gc] = a[1];
                o[(size_t)(gr + 2) * 256 + gc] = a[2];
                o[(size_t)(gr + 3) * 256 + gc] = a[3];
            } else {
                float* o = dout + O_SIG;
                const int c = gc - 256;
                o[(size_t)(gr + 0) * 128 + c] = a[0];
                o[(size_t)(gr + 1) * 128 + c] = a[1];
                o[(size_t)(gr + 2) * 128 + c] = a[2];
                o[(size_t)(gr + 3) * 128 + c] = a[3];
            }
        } else {
            float* p = ws + W_K4P;
            p[(size_t)(gr + 0) * 384 + gc] = a[0];
            p[(size_t)(gr + 1) * 384 + gc] = a[1];
            p[(size_t)(gr + 2) * 384 + gc] = a[2];
            p[(size_t)(gr + 3) * 384 + gc] = a[3];
        }
    }
}

// ---------------------------------------------------------------------------
// K4b: dout(delta|sig) += ws partial from ksplit 1. 786432 float4 elements.
// ---------------------------------------------------------------------------
__global__ __launch_bounds__(256)
void k4b_reduce(const float* __restrict__ ws, float* __restrict__ dout)
{
    const int idx = blockIdx.x * 256 + threadIdx.x;         // 3072 blocks
    const int row = idx / 96;                               // 96 float4-cols per row
    const int c   = (idx - row * 96) * 4;
    const float4 p = *(const float4*)&ws[W_K4P + (size_t)row * 384 + c];
    float* dst = (c < 256) ? (dout + O_DELTA + (size_t)row * 256 + c)
                           : (dout + O_SIG   + (size_t)row * 128 + (c - 256));
    float4 d = *(float4*)dst;
    d.x += p.x; d.y += p.y; d.z += p.z; d.w += p.w;
    *(float4*)dst = d;
}

// ---------------------------------------------------------------------------
extern "C" void kernel_launch(void* const* d_in, const int* in_sizes, int n_in,
                              void* d_out, int out_size, void* d_ws, size_t ws_size,
                              hipStream_t stream)
{
    const float* qu   = (const float*)d_in[0];
    const float* qb   = (const float*)d_in[1];
    const float* qsig = (const float*)d_in[2];
    const float* drp  = (const float*)d_in[3];
    const float* spr  = (const float*)d_in[4];
    const float* wm   = (const float*)d_in[5];
    const float* ec   = (const float*)d_in[6];
    float* out = (float*)d_out;
    float* ws  = (float*)d_ws;

    kprep<<<5633, 256, 0, stream>>>(qu, qb, qsig, drp, spr, wm, ec, ws);
    k3_mfma<<<dim3(128, 32), 256, 0, stream>>>(ws, out);
    k3b_stats<<<32, 256, 0, stream>>>(ws, out);
    k4_mfma<<<256, 512, 0, stream>>>(ws, out);
    k4b_reduce<<<3072, 256, 0, stream>>>(ws, out);
}